// Round 9
// baseline (229.452 us; speedup 1.0000x reference)
//
#include <hip/hip_runtime.h>

#define NN 50000
#define NE 600000

typedef unsigned short ushort_t;
typedef ushort_t ushortx8 __attribute__((ext_vector_type(8)));
typedef ushort_t ushortx4 __attribute__((ext_vector_type(4)));
typedef short bf16x8 __attribute__((ext_vector_type(8)));
typedef float f32x4 __attribute__((ext_vector_type(4)));
typedef float fltx4 __attribute__((ext_vector_type(4)));

__device__ __forceinline__ float bf2f(ushort_t u) {
    union { unsigned int i; float f; } c;
    c.i = ((unsigned int)u) << 16;
    return c.f;
}
__device__ __forceinline__ ushort_t f2bf(float f) {
    union { float f; unsigned int i; } c;
    c.f = f;
    unsigned int u = c.i;
    unsigned int r = u + 0x7FFFu + ((u >> 16) & 1u);   // RNE
    return (ushort_t)(r >> 16);
}
__device__ __forceinline__ unsigned cvtpk(float lo, float hi) {
    unsigned r;
    asm("v_cvt_pk_bf16_f32 %0, %1, %2" : "=v"(r) : "v"(lo), "v"(hi));
    return r;
}

// ---------------- merged: x->bf16 (blocks 0..3124) | degree count (rest) --------
__global__ void k_pre(const float* __restrict__ X, ushort_t* __restrict__ XB,
                      const int* __restrict__ ei, int* __restrict__ cnt) {
    int b = blockIdx.x;
    if (b < 3125) {
        size_t i = (size_t)b * 256 + threadIdx.x;
        const float4* X4 = (const float4*)X;
        float4 a = X4[i * 2], c4 = X4[i * 2 + 1];
        union { unsigned u[4]; ushortx8 v; } cv;
        cv.u[0] = cvtpk(a.x, a.y);
        cv.u[1] = cvtpk(a.z, a.w);
        cv.u[2] = cvtpk(c4.x, c4.y);
        cv.u[3] = cvtpk(c4.z, c4.w);
        __builtin_nontemporal_store(cv.v, (ushortx8*)XB + i);
    } else {
        int e = (b - 3125) * 256 + threadIdx.x;
        if (e < NE) {
            int d = __builtin_nontemporal_load(ei + NE + e);
            atomicAdd(&cnt[d], 1);
        }
    }
}

// scan of cnt -> rowptr (exclusive, per-block) + block sums; also dinv
__global__ void k_scan1(const int* __restrict__ cnt, int* __restrict__ rowptr,
                        int* __restrict__ bsum, float* __restrict__ dinv) {
    __shared__ int s[256];
    int t = threadIdx.x;
    int i = blockIdx.x * 256 + t;
    int v = (i < NN) ? cnt[i] : 0;
    if (i < NN) dinv[i] = rsqrtf(1.0f + (float)v);
    s[t] = v;
    __syncthreads();
    for (int d = 1; d < 256; d <<= 1) {
        int tmp = (t >= d) ? s[t - d] : 0;
        __syncthreads();
        s[t] += tmp;
        __syncthreads();
    }
    if (i < NN) rowptr[i] = s[t] - v;
    if (t == 255) bsum[blockIdx.x] = s[255];
}

// blocks 0..255: weight prep (transpose + bf16). block 256: scan of bsum -> boff.
__global__ void k_scan2_prep(int* __restrict__ bsum, int* __restrict__ boff, int nb,
                             const float* __restrict__ Wp1, const float* __restrict__ Wv1,
                             const float* __restrict__ Wp2, const float* __restrict__ Wv2,
                             ushort_t* __restrict__ Wt1, ushort_t* __restrict__ Wt2p,
                             ushort_t* __restrict__ Wt2v) {
    int b = blockIdx.x, t = threadIdx.x;
    if (b < 128) {
        int idx = b * 256 + t;
        int n = idx >> 7, k = idx & 127;
        float v = (n < 128) ? Wp1[k * 128 + n] : Wv1[k * 128 + (n - 128)];
        Wt1[n * 128 + k] = f2bf(v);
    } else if (b < 192) {
        int idx = (b - 128) * 256 + t;
        int n = idx >> 7, k = idx & 127;
        Wt2p[n * 128 + k] = f2bf(Wp2[k * 128 + n]);
    } else if (b < 256) {
        int idx = (b - 192) * 256 + t;
        int n = idx >> 7, k = idx & 127;
        Wt2v[n * 128 + k] = f2bf(Wv2[k * 128 + n]);
    } else {
        __shared__ int s[256];
        int v = (t < nb) ? bsum[t] : 0;
        s[t] = v;
        __syncthreads();
        for (int d = 1; d < 256; d <<= 1) {
            int tmp = (t >= d) ? s[t - d] : 0;
            __syncthreads();
            s[t] += tmp;
            __syncthreads();
        }
        boff[t] = s[t] - v;
    }
}

// rc[i] = {final_start, cnt}
__global__ void k_scan3rc(const int* __restrict__ rowptr, const int* __restrict__ cnt,
                          const int* __restrict__ boff, int2* __restrict__ rc) {
    int i = blockIdx.x * 256 + threadIdx.x;
    if (i < NN) {
        int2 v;
        v.x = rowptr[i] + boff[blockIdx.x];
        v.y = cnt[i];
        rc[i] = v;
    }
}

// scatter src ids into CSR slots (weights computed lazily in the agg kernels)
__global__ void k_fill(const int* __restrict__ ei, const int2* __restrict__ rc,
                       int* __restrict__ fill, int* __restrict__ edges) {
    int e = blockIdx.x * 256 + threadIdx.x;
    if (e < NE) {
        int s = __builtin_nontemporal_load(ei + e);
        int d = __builtin_nontemporal_load(ei + NE + e);
        int pos = rc[d].x + atomicAdd(&fill[d], 1);
        edges[pos] = s;
    }
}

// ---------------- aggregation, 128 features bf16 (layer-1 input x) --------------
// wave per node; 4 teams of 16 lanes (16B each = 256B row). Predicated 4-slot
// burst; dead slots gather row i (L1-hot) with weight 0.
__global__ __launch_bounds__(256) void k_agg128(const ushort_t* __restrict__ H,
                                                ushort_t* __restrict__ OUT,
                                                const float* __restrict__ dinv,
                                                const int2* __restrict__ rc,
                                                const int* __restrict__ edges) {
    int wv = threadIdx.x >> 6;
    int l = threadIdx.x & 63;
    int i = blockIdx.x * 4 + wv;
    if (i >= NN) return;
    int t2 = l >> 4, q = l & 15;
    const ushortx8* H8 = (const ushortx8*)H;

    float a0[8] = {}, a1[8] = {};
    float di = dinv[i];
    float ws = (t2 == 0) ? di * di : 0.f;
    ushortx8 hv = H8[(size_t)i * 16 + q];
#pragma unroll
    for (int k = 0; k < 8; ++k) a0[k] = ws * bf2f(hv[k]);

    int2 rcv = rc[i];
    int st = rcv.x, n = rcv.y;

    for (int j = t2; j < n; j += 16) {
        int idx[4];
        float w[4];
#pragma unroll
        for (int s = 0; s < 4; ++s) {
            int jj = j + 4 * s;
            bool valid = jj < n;
            int em = __builtin_nontemporal_load(edges + (valid ? st + jj : st));
            idx[s] = valid ? em : i;
            w[s] = valid ? dinv[em] * di : 0.f;
        }
        ushortx8 hh[4];
#pragma unroll
        for (int s = 0; s < 4; ++s) hh[s] = H8[(size_t)idx[s] * 16 + q];
#pragma unroll
        for (int k = 0; k < 8; ++k) a0[k] += w[0] * bf2f(hh[0][k]);
#pragma unroll
        for (int k = 0; k < 8; ++k) a1[k] += w[1] * bf2f(hh[1][k]);
#pragma unroll
        for (int k = 0; k < 8; ++k) a0[k] += w[2] * bf2f(hh[2][k]);
#pragma unroll
        for (int k = 0; k < 8; ++k) a1[k] += w[3] * bf2f(hh[3][k]);
    }
#pragma unroll
    for (int k = 0; k < 8; ++k) a0[k] += a1[k];
#pragma unroll
    for (int k = 0; k < 8; ++k) {
        a0[k] += __shfl_xor(a0[k], 16, 64);
        a0[k] += __shfl_xor(a0[k], 32, 64);
    }
    if (l < 16) {
        ushortx8 o = {f2bf(a0[0]), f2bf(a0[1]), f2bf(a0[2]), f2bf(a0[3]),
                      f2bf(a0[4]), f2bf(a0[5]), f2bf(a0[6]), f2bf(a0[7])};
        __builtin_nontemporal_store(o, (ushortx8*)OUT + (size_t)i * 16 + q);
    }
}

// ---------------- aggregation, 256 features bf16, plain ----------
__global__ __launch_bounds__(256) void k_agg256(const ushort_t* __restrict__ H,
                                                ushort_t* __restrict__ OUT,
                                                const float* __restrict__ dinv,
                                                const int2* __restrict__ rc,
                                                const int* __restrict__ edges) {
    int wv = threadIdx.x >> 6;
    int l = threadIdx.x & 63;
    int i = blockIdx.x * 4 + wv;
    if (i >= NN) return;
    int h = l >> 5, q = l & 31;
    const ushortx8* H8 = (const ushortx8*)H;

    float a0[8] = {}, a1[8] = {};
    float di = dinv[i];
    float ws = (h == 0) ? di * di : 0.f;
    ushortx8 hv = H8[(size_t)i * 32 + q];
#pragma unroll
    for (int k = 0; k < 8; ++k) a0[k] = ws * bf2f(hv[k]);

    int2 rcv = rc[i];
    int st = rcv.x, n = rcv.y;

    for (int j = h; j < n; j += 8) {
        int idx[4];
        float w[4];
#pragma unroll
        for (int s = 0; s < 4; ++s) {
            int jj = j + 2 * s;
            bool valid = jj < n;
            int em = __builtin_nontemporal_load(edges + (valid ? st + jj : st));
            idx[s] = valid ? em : i;
            w[s] = valid ? dinv[em] * di : 0.f;
        }
        ushortx8 hh[4];
#pragma unroll
        for (int s = 0; s < 4; ++s) hh[s] = H8[(size_t)idx[s] * 32 + q];
#pragma unroll
        for (int k = 0; k < 8; ++k) a0[k] += w[0] * bf2f(hh[0][k]);
#pragma unroll
        for (int k = 0; k < 8; ++k) a1[k] += w[1] * bf2f(hh[1][k]);
#pragma unroll
        for (int k = 0; k < 8; ++k) a0[k] += w[2] * bf2f(hh[2][k]);
#pragma unroll
        for (int k = 0; k < 8; ++k) a1[k] += w[3] * bf2f(hh[3][k]);
    }
#pragma unroll
    for (int k = 0; k < 8; ++k) a0[k] += a1[k];
#pragma unroll
    for (int k = 0; k < 8; ++k) a0[k] += __shfl_xor(a0[k], 32, 64);

    if (h == 0) {
        ushortx8 o = {f2bf(a0[0]), f2bf(a0[1]), f2bf(a0[2]), f2bf(a0[3]),
                      f2bf(a0[4]), f2bf(a0[5]), f2bf(a0[6]), f2bf(a0[7])};
        __builtin_nontemporal_store(o, (ushortx8*)OUT + (size_t)i * 32 + q);
    }
}

// ---------------- layer-1 MFMA GEMM: f1 = relu(ag0[N,128] @ [Wp1|Wv1] + b) -------
__global__ __launch_bounds__(256) void k_gemm1(const ushort_t* __restrict__ A,
                                               const ushort_t* __restrict__ Wt1,
                                               const float* __restrict__ bL,
                                               const float* __restrict__ bH,
                                               ushort_t* __restrict__ C, int nrows) {
    __shared__ ushort_t Wl[256 * 128];
    int t = threadIdx.x;
    const ushortx8* Wg = (const ushortx8*)Wt1;
#pragma unroll
    for (int i = 0; i < 16; ++i) {
        int c = i * 256 + t;
        int row = c >> 4, slot = c & 15;
        int db = row * 256 + ((slot * 16) ^ ((row & 7) << 4));
        *(ushortx8*)((char*)Wl + db) = Wg[c];
    }
    __syncthreads();

    int w = t >> 6, l = t & 63, m = l & 15, g = l >> 4;
    int r0 = blockIdx.x * 64 + w * 16;
    if (r0 >= nrows) return;

    const ushort_t* Arow = A + (size_t)(r0 + m) * 128;
    bf16x8 af[4];
#pragma unroll
    for (int kk = 0; kk < 4; ++kk) af[kk] = *(const bf16x8*)(Arow + kk * 32 + g * 8);

    f32x4 acc[16];
#pragma unroll
    for (int nt = 0; nt < 16; ++nt) acc[nt] = (f32x4){0.f, 0.f, 0.f, 0.f};
    int sw = (m & 7) << 4;
#pragma unroll
    for (int nt = 0; nt < 16; ++nt) {
        const char* Wb = (const char*)Wl + (nt * 16 + m) * 256;
#pragma unroll
        for (int kk = 0; kk < 4; ++kk) {
            bf16x8 wf = *(const bf16x8*)(Wb + ((kk * 64 + g * 16) ^ sw));
            acc[nt] = __builtin_amdgcn_mfma_f32_16x16x32_bf16(wf, af[kk], acc[nt], 0, 0, 0);
        }
    }
#pragma unroll
    for (int nt = 0; nt < 16; ++nt) {
        const float* bb = (nt < 8) ? (bL + nt * 16 + g * 4) : (bH + (nt - 8) * 16 + g * 4);
        float4 bv = *(const float4*)bb;
        ushortx4 o = {f2bf(fmaxf(acc[nt][0] + bv.x, 0.f)),
                      f2bf(fmaxf(acc[nt][1] + bv.y, 0.f)),
                      f2bf(fmaxf(acc[nt][2] + bv.z, 0.f)),
                      f2bf(fmaxf(acc[nt][3] + bv.w, 0.f))};
        *(ushortx4*)(C + (size_t)(r0 + m) * 256 + nt * 16 + g * 4) = o;
    }
}

// ---- layer-2 dual MFMA GEMM fused with layer-3 projection -----------------------
// f2 = relu(ag1 @ blockdiag(Wp2,Wv2) + b) computed in registers, then
// fs[:,0:8] = f2[:,0:128] @ Wp3 ; fs[:,8] = f2[:,128:256] @ Wv3. f2 never stored.
__global__ __launch_bounds__(256) void k_gemm2s(const ushort_t* __restrict__ A,
                                                const ushort_t* __restrict__ Wp,
                                                const ushort_t* __restrict__ Wv,
                                                const float* __restrict__ bL,
                                                const float* __restrict__ bH,
                                                const float* __restrict__ Wp3,
                                                const float* __restrict__ Wv3,
                                                float* __restrict__ FS, int nrows) {
    __shared__ ushort_t Wl[2 * 128 * 128];   // 64KB
    __shared__ float W3c[9][128];            // 4.5KB, SoA: W3c[c][k]
    int t = threadIdx.x;
    const ushortx8* Wgp = (const ushortx8*)Wp;
    const ushortx8* Wgv = (const ushortx8*)Wv;
#pragma unroll
    for (int i = 0; i < 8; ++i) {
        int c = i * 256 + t;
        int row = c >> 4, slot = c & 15;
        int db = row * 256 + ((slot * 16) ^ ((row & 7) << 4));
        *(ushortx8*)((char*)Wl + db) = Wgp[c];
        *(ushortx8*)((char*)Wl + 32768 + db) = Wgv[c];
    }
    for (int jj = t; jj < 1152; jj += 256) {
        int c = jj >> 7, k = jj & 127;
        W3c[c][k] = (c < 8) ? Wp3[k * 8 + c] : Wv3[k];
    }
    __syncthreads();

    int w = t >> 6, l = t & 63, m = l & 15, g = l >> 4;
    int r0 = blockIdx.x * 64 + w * 16;
    if (r0 >= nrows) return;

    const ushort_t* Arow = A + (size_t)(r0 + m) * 256;
    bf16x8 alo[4], ahi[4];
#pragma unroll
    for (int kk = 0; kk < 4; ++kk) {
        alo[kk] = *(const bf16x8*)(Arow + kk * 32 + g * 8);
        ahi[kk] = *(const bf16x8*)(Arow + 128 + kk * 32 + g * 8);
    }

    f32x4 accp[8], accv[8];
#pragma unroll
    for (int nt = 0; nt < 8; ++nt) {
        accp[nt] = (f32x4){0.f, 0.f, 0.f, 0.f};
        accv[nt] = (f32x4){0.f, 0.f, 0.f, 0.f};
    }
    int sw = (m & 7) << 4;
#pragma unroll
    for (int nt = 0; nt < 8; ++nt) {
        const char* Wbp = (const char*)Wl + (nt * 16 + m) * 256;
        const char* Wbv = Wbp + 32768;
#pragma unroll
        for (int kk = 0; kk < 4; ++kk) {
            int off = (kk * 64 + g * 16) ^ sw;
            bf16x8 wfp = *(const bf16x8*)(Wbp + off);
            accp[nt] = __builtin_amdgcn_mfma_f32_16x16x32_bf16(wfp, alo[kk], accp[nt], 0, 0, 0);
            bf16x8 wfv = *(const bf16x8*)(Wbv + off);
            accv[nt] = __builtin_amdgcn_mfma_f32_16x16x32_bf16(wfv, ahi[kk], accv[nt], 0, 0, 0);
        }
    }

    // bias + relu in registers (lane holds cols nt*16+g*4+j of row r0+m, both halves)
    float rp[8][4], rv[8][4];
#pragma unroll
    for (int nt = 0; nt < 8; ++nt) {
        float4 bp = *(const float4*)(bL + nt * 16 + g * 4);
        float4 bv = *(const float4*)(bH + nt * 16 + g * 4);
        rp[nt][0] = fmaxf(accp[nt][0] + bp.x, 0.f);
        rp[nt][1] = fmaxf(accp[nt][1] + bp.y, 0.f);
        rp[nt][2] = fmaxf(accp[nt][2] + bp.z, 0.f);
        rp[nt][3] = fmaxf(accp[nt][3] + bp.w, 0.f);
        rv[nt][0] = fmaxf(accv[nt][0] + bv.x, 0.f);
        rv[nt][1] = fmaxf(accv[nt][1] + bv.y, 0.f);
        rv[nt][2] = fmaxf(accv[nt][2] + bv.z, 0.f);
        rv[nt][3] = fmaxf(accv[nt][3] + bv.w, 0.f);
    }

    // project to 9 outputs: partial over this lane's 32 k's, then reduce over g
    float ps[9] = {};
#pragma unroll
    for (int c = 0; c < 8; ++c) {
#pragma unroll
        for (int nt = 0; nt < 8; ++nt) {
            float4 w4 = *(const float4*)&W3c[c][nt * 16 + g * 4];
            ps[c] += rp[nt][0] * w4.x + rp[nt][1] * w4.y + rp[nt][2] * w4.z + rp[nt][3] * w4.w;
        }
    }
#pragma unroll
    for (int nt = 0; nt < 8; ++nt) {
        float4 w4 = *(const float4*)&W3c[8][nt * 16 + g * 4];
        ps[8] += rv[nt][0] * w4.x + rv[nt][1] * w4.y + rv[nt][2] * w4.z + rv[nt][3] * w4.w;
    }
#pragma unroll
    for (int c = 0; c < 9; ++c) {
        ps[c] += __shfl_xor(ps[c], 16, 64);
        ps[c] += __shfl_xor(ps[c], 32, 64);
    }
    if (g == 0) {
        float* o = FS + (size_t)(r0 + m) * 12;
        fltx4 o0 = {ps[0], ps[1], ps[2], ps[3]};
        fltx4 o1 = {ps[4], ps[5], ps[6], ps[7]};
        __builtin_nontemporal_store(o0, (fltx4*)o);
        __builtin_nontemporal_store(o1, (fltx4*)o + 1);
        __builtin_nontemporal_store(ps[8], o + 8);
    }
}

// ---------------- final fused aggregation (8 logits + 1 value) ----------------
__global__ void k_agg9(const float* __restrict__ FS, float* __restrict__ out_logits,
                       float* __restrict__ out_v, const float* __restrict__ bp3,
                       const float* __restrict__ bv3, const float* __restrict__ dinv,
                       const int2* __restrict__ rc, const int* __restrict__ edges) {
    int i = blockIdx.x * 256 + threadIdx.x;
    if (i >= NN) return;
    float di = dinv[i];
    float w0 = di * di;
    const float4* F = (const float4*)FS;
    size_t b0 = (size_t)i * 3;
    float4 x0 = F[b0], x1 = F[b0 + 1], x2 = F[b0 + 2];
    float a[9];
    a[0] = w0 * x0.x; a[1] = w0 * x0.y; a[2] = w0 * x0.z; a[3] = w0 * x0.w;
    a[4] = w0 * x1.x; a[5] = w0 * x1.y; a[6] = w0 * x1.z; a[7] = w0 * x1.w;
    a[8] = w0 * x2.x;
    int2 rcv = rc[i];
    int st = rcv.x, n = rcv.y;
    for (int j = 0; j < n; ++j) {
        int e = edges[st + j];
        float w = dinv[e] * di;
        size_t sb = (size_t)e * 3;
        float4 y0 = F[sb], y1 = F[sb + 1], y2 = F[sb + 2];
        a[0] += w * y0.x; a[1] += w * y0.y; a[2] += w * y0.z; a[3] += w * y0.w;
        a[4] += w * y1.x; a[5] += w * y1.y; a[6] += w * y1.z; a[7] += w * y1.w;
        a[8] += w * y2.x;
    }
    float4 bpa = *(const float4*)bp3;
    float4 bpb = *(const float4*)(bp3 + 4);
    fltx4 o0 = {a[0] + bpa.x, a[1] + bpa.y, a[2] + bpa.z, a[3] + bpa.w};
    fltx4 o1 = {a[4] + bpb.x, a[5] + bpb.y, a[6] + bpb.z, a[7] + bpb.w};
    __builtin_nontemporal_store(o0, (fltx4*)out_logits + (size_t)i * 2);
    __builtin_nontemporal_store(o1, (fltx4*)out_logits + (size_t)i * 2 + 1);
    __builtin_nontemporal_store(a[8] + bv3[0], out_v + i);
}

// ---------------- launcher ----------------
extern "C" void kernel_launch(void* const* d_in, const int* in_sizes, int n_in,
                              void* d_out, int out_size, void* d_ws, size_t ws_size,
                              hipStream_t stream) {
    const float* x   = (const float*)d_in[0];
    const int*   ei  = (const int*)d_in[1];
    const float* Wp1 = (const float*)d_in[2],  *bp1 = (const float*)d_in[3];
    const float* Wp2 = (const float*)d_in[4],  *bp2 = (const float*)d_in[5];
    const float* Wp3 = (const float*)d_in[6],  *bp3 = (const float*)d_in[7];
    const float* Wv1 = (const float*)d_in[8],  *bv1 = (const float*)d_in[9];
    const float* Wv2 = (const float*)d_in[10], *bv2 = (const float*)d_in[11];
    const float* Wv3 = (const float*)d_in[12], *bv3 = (const float*)d_in[13];
    float* out_logits = (float*)d_out;
    float* out_v = (float*)d_out + (size_t)NN * 8;

    char* w = (char*)d_ws;
    auto alloc = [&](size_t bytes) {
        char* p = w;
        w += (bytes + 255) & ~(size_t)255;
        return p;
    };
    int*      cntfill = (int*)alloc((size_t)2 * NN * 4);
    int*      cnt    = cntfill;
    int*      fill   = cntfill + NN;
    int*      rowptr = (int*)alloc(NN * 4);
    int*      bsum   = (int*)alloc(256 * 4);
    int*      boff   = (int*)alloc(256 * 4);
    float*    dinv   = (float*)alloc(NN * 4);
    int2*     rc     = (int2*)alloc((size_t)NN * 8);
    int*      edges  = (int*)alloc((size_t)NE * 4);
    ushort_t* Wt1    = (ushort_t*)alloc(256 * 128 * 2);
    ushort_t* Wt2p   = (ushort_t*)alloc(128 * 128 * 2);
    ushort_t* Wt2v   = (ushort_t*)alloc(128 * 128 * 2);
    ushort_t* xb     = (ushort_t*)alloc((size_t)NN * 128 * 2);
    ushort_t* ag0    = (ushort_t*)alloc((size_t)NN * 128 * 2);
    ushort_t* f1b    = (ushort_t*)alloc((size_t)NN * 256 * 2);
    ushort_t* ag1    = (ushort_t*)alloc((size_t)NN * 256 * 2);
    float*    fs     = (float*)alloc((size_t)NN * 12 * 4);

    const int NB = (NN + 255) / 256;   // 196
    const int EB = (NE + 255) / 256;   // 2344
    const int GB = (NN + 63) / 64;     // 782
    const int AB = NN / 4;             // 12500

    (void)hipMemsetAsync(cntfill, 0, (size_t)2 * NN * 4, stream);
    k_pre<<<3125 + EB, 256, 0, stream>>>(x, xb, ei, cnt);
    k_scan1<<<NB, 256, 0, stream>>>(cnt, rowptr, bsum, dinv);
    k_scan2_prep<<<257, 256, 0, stream>>>(bsum, boff, NB, Wp1, Wv1, Wp2, Wv2,
                                          Wt1, Wt2p, Wt2v);
    k_scan3rc<<<NB, 256, 0, stream>>>(rowptr, cnt, boff, rc);
    k_fill<<<EB, 256, 0, stream>>>(ei, rc, fill, edges);

    // layer 1: agg(x) then GEMM (+bias+relu)   [agg(x@W) == agg(x)@W]
    k_agg128<<<AB, 256, 0, stream>>>(xb, ag0, dinv, rc, edges);
    k_gemm1<<<GB, 256, 0, stream>>>(ag0, Wt1, bp1, bv1, f1b, NN);
    // layer 2: agg(f1), then fused {GEMM2 + bias + relu + layer-3 projection}
    k_agg256<<<AB, 256, 0, stream>>>(f1b, ag1, dinv, rc, edges);
    k_gemm2s<<<GB, 256, 0, stream>>>(ag1, Wt2p, Wt2v, bp2, bv2, Wp3, Wv3, fs, NN);
    // layer 3 gather
    k_agg9<<<NB, 256, 0, stream>>>(fs, out_logits, out_v, bp3, bv3, dinv, rc, edges);
}

// Round 10
// 206.980 us; speedup vs baseline: 1.1086x; 1.1086x over previous
//
#include <hip/hip_runtime.h>

#define NN 50000
#define NE 600000

typedef unsigned short ushort_t;
typedef ushort_t ushortx8 __attribute__((ext_vector_type(8)));
typedef ushort_t ushortx4 __attribute__((ext_vector_type(4)));
typedef short bf16x8 __attribute__((ext_vector_type(8)));
typedef float f32x4 __attribute__((ext_vector_type(4)));
typedef int intx2 __attribute__((ext_vector_type(2)));
typedef float fltx4 __attribute__((ext_vector_type(4)));

__device__ __forceinline__ float bf2f(ushort_t u) {
    union { unsigned int i; float f; } c;
    c.i = ((unsigned int)u) << 16;
    return c.f;
}
__device__ __forceinline__ ushort_t f2bf(float f) {
    union { float f; unsigned int i; } c;
    c.f = f;
    unsigned int u = c.i;
    unsigned int r = u + 0x7FFFu + ((u >> 16) & 1u);   // RNE
    return (ushort_t)(r >> 16);
}
__device__ __forceinline__ unsigned cvtpk(float lo, float hi) {
    unsigned r;
    asm("v_cvt_pk_bf16_f32 %0, %1, %2" : "=v"(r) : "v"(lo), "v"(hi));
    return r;
}

// ---------------- merged: x->bf16 (blocks 0..3124) | degree count (rest) --------
__global__ void k_pre(const float* __restrict__ X, ushort_t* __restrict__ XB,
                      const int* __restrict__ ei, int* __restrict__ cnt) {
    int b = blockIdx.x;
    if (b < 3125) {
        size_t i = (size_t)b * 256 + threadIdx.x;
        const float4* X4 = (const float4*)X;
        float4 a = X4[i * 2], c4 = X4[i * 2 + 1];
        union { unsigned u[4]; ushortx8 v; } cv;
        cv.u[0] = cvtpk(a.x, a.y);
        cv.u[1] = cvtpk(a.z, a.w);
        cv.u[2] = cvtpk(c4.x, c4.y);
        cv.u[3] = cvtpk(c4.z, c4.w);
        __builtin_nontemporal_store(cv.v, (ushortx8*)XB + i);
    } else {
        int e = (b - 3125) * 256 + threadIdx.x;
        if (e < NE) {
            int d = __builtin_nontemporal_load(ei + NE + e);
            atomicAdd(&cnt[d], 1);
        }
    }
}

// scan of cnt -> rowptr (exclusive, per-block) + block sums; also dinv
__global__ void k_scan1(const int* __restrict__ cnt, int* __restrict__ rowptr,
                        int* __restrict__ bsum, float* __restrict__ dinv) {
    __shared__ int s[256];
    int t = threadIdx.x;
    int i = blockIdx.x * 256 + t;
    int v = (i < NN) ? cnt[i] : 0;
    if (i < NN) dinv[i] = rsqrtf(1.0f + (float)v);
    s[t] = v;
    __syncthreads();
    for (int d = 1; d < 256; d <<= 1) {
        int tmp = (t >= d) ? s[t - d] : 0;
        __syncthreads();
        s[t] += tmp;
        __syncthreads();
    }
    if (i < NN) rowptr[i] = s[t] - v;
    if (t == 255) bsum[blockIdx.x] = s[255];
}

// blocks 0..255: weight prep (transpose + bf16). block 256: scan of bsum -> boff.
__global__ void k_scan2_prep(int* __restrict__ bsum, int* __restrict__ boff, int nb,
                             const float* __restrict__ Wp1, const float* __restrict__ Wv1,
                             const float* __restrict__ Wp2, const float* __restrict__ Wv2,
                             ushort_t* __restrict__ Wt1, ushort_t* __restrict__ Wt2p,
                             ushort_t* __restrict__ Wt2v) {
    int b = blockIdx.x, t = threadIdx.x;
    if (b < 128) {
        int idx = b * 256 + t;
        int n = idx >> 7, k = idx & 127;
        float v = (n < 128) ? Wp1[k * 128 + n] : Wv1[k * 128 + (n - 128)];
        Wt1[n * 128 + k] = f2bf(v);
    } else if (b < 192) {
        int idx = (b - 128) * 256 + t;
        int n = idx >> 7, k = idx & 127;
        Wt2p[n * 128 + k] = f2bf(Wp2[k * 128 + n]);
    } else if (b < 256) {
        int idx = (b - 192) * 256 + t;
        int n = idx >> 7, k = idx & 127;
        Wt2v[n * 128 + k] = f2bf(Wv2[k * 128 + n]);
    } else {
        __shared__ int s[256];
        int v = (t < nb) ? bsum[t] : 0;
        s[t] = v;
        __syncthreads();
        for (int d = 1; d < 256; d <<= 1) {
            int tmp = (t >= d) ? s[t - d] : 0;
            __syncthreads();
            s[t] += tmp;
            __syncthreads();
        }
        boff[t] = s[t] - v;
    }
}

// rc[i] = {final_start, cnt}
__global__ void k_scan3rc(const int* __restrict__ rowptr, const int* __restrict__ cnt,
                          const int* __restrict__ boff, int2* __restrict__ rc) {
    int i = blockIdx.x * 256 + threadIdx.x;
    if (i < NN) {
        int2 v;
        v.x = rowptr[i] + boff[blockIdx.x];
        v.y = cnt[i];
        rc[i] = v;
    }
}

// scatter {src, weight} into CSR slots
__global__ void k_fill(const int* __restrict__ ei, const int2* __restrict__ rc,
                       int* __restrict__ fill, const float* __restrict__ dinv,
                       int2* __restrict__ edges) {
    int e = blockIdx.x * 256 + threadIdx.x;
    if (e < NE) {
        int s = __builtin_nontemporal_load(ei + e);
        int d = __builtin_nontemporal_load(ei + NE + e);
        int pos = rc[d].x + atomicAdd(&fill[d], 1);
        int2 pr;
        pr.x = s;
        pr.y = __float_as_int(dinv[s] * dinv[d]);
        edges[pos] = pr;
    }
}

// ---------------- aggregation, 128 features bf16 (layer-1 input x) --------------
// wave per node; 4 teams of 16 lanes (16B each = 256B row). Predicated 4-slot
// burst; dead slots gather row i (L1-hot) with weight 0.
__global__ __launch_bounds__(256) void k_agg128(const ushort_t* __restrict__ H,
                                                ushort_t* __restrict__ OUT,
                                                const float* __restrict__ dinv,
                                                const int2* __restrict__ rc,
                                                const int2* __restrict__ edges) {
    int wv = threadIdx.x >> 6;
    int l = threadIdx.x & 63;
    int i = blockIdx.x * 4 + wv;
    if (i >= NN) return;
    int t2 = l >> 4, q = l & 15;
    const ushortx8* H8 = (const ushortx8*)H;

    float a0[8] = {}, a1[8] = {};
    float di = dinv[i];
    float ws = (t2 == 0) ? di * di : 0.f;
    ushortx8 hv = H8[(size_t)i * 16 + q];
#pragma unroll
    for (int k = 0; k < 8; ++k) a0[k] = ws * bf2f(hv[k]);

    int2 rcv = rc[i];
    int st = rcv.x, n = rcv.y;

    for (int j = t2; j < n; j += 16) {
        int idx[4];
        float w[4];
#pragma unroll
        for (int s = 0; s < 4; ++s) {
            int jj = j + 4 * s;
            bool valid = jj < n;
            intx2 em = __builtin_nontemporal_load(
                (const intx2*)edges + (valid ? st + jj : st));
            idx[s] = valid ? em.x : i;
            w[s] = valid ? __int_as_float(em.y) : 0.f;
        }
        ushortx8 hh[4];
#pragma unroll
        for (int s = 0; s < 4; ++s) hh[s] = H8[(size_t)idx[s] * 16 + q];
#pragma unroll
        for (int k = 0; k < 8; ++k) a0[k] += w[0] * bf2f(hh[0][k]);
#pragma unroll
        for (int k = 0; k < 8; ++k) a1[k] += w[1] * bf2f(hh[1][k]);
#pragma unroll
        for (int k = 0; k < 8; ++k) a0[k] += w[2] * bf2f(hh[2][k]);
#pragma unroll
        for (int k = 0; k < 8; ++k) a1[k] += w[3] * bf2f(hh[3][k]);
    }
#pragma unroll
    for (int k = 0; k < 8; ++k) a0[k] += a1[k];
#pragma unroll
    for (int k = 0; k < 8; ++k) {
        a0[k] += __shfl_xor(a0[k], 16, 64);
        a0[k] += __shfl_xor(a0[k], 32, 64);
    }
    if (l < 16) {
        ushortx8 o = {f2bf(a0[0]), f2bf(a0[1]), f2bf(a0[2]), f2bf(a0[3]),
                      f2bf(a0[4]), f2bf(a0[5]), f2bf(a0[6]), f2bf(a0[7])};
        __builtin_nontemporal_store(o, (ushortx8*)OUT + (size_t)i * 16 + q);
    }
}

// ---------------- aggregation, 256 features bf16, plain ----------
__global__ __launch_bounds__(256) void k_agg256(const ushort_t* __restrict__ H,
                                                ushort_t* __restrict__ OUT,
                                                const float* __restrict__ dinv,
                                                const int2* __restrict__ rc,
                                                const int2* __restrict__ edges) {
    int wv = threadIdx.x >> 6;
    int l = threadIdx.x & 63;
    int i = blockIdx.x * 4 + wv;
    if (i >= NN) return;
    int h = l >> 5, q = l & 31;
    const ushortx8* H8 = (const ushortx8*)H;

    float a0[8] = {}, a1[8] = {};
    float di = dinv[i];
    float ws = (h == 0) ? di * di : 0.f;
    ushortx8 hv = H8[(size_t)i * 32 + q];
#pragma unroll
    for (int k = 0; k < 8; ++k) a0[k] = ws * bf2f(hv[k]);

    int2 rcv = rc[i];
    int st = rcv.x, n = rcv.y;

    for (int j = h; j < n; j += 8) {
        int idx[4];
        float w[4];
#pragma unroll
        for (int s = 0; s < 4; ++s) {
            int jj = j + 2 * s;
            bool valid = jj < n;
            intx2 em = __builtin_nontemporal_load(
                (const intx2*)edges + (valid ? st + jj : st));
            idx[s] = valid ? em.x : i;
            w[s] = valid ? __int_as_float(em.y) : 0.f;
        }
        ushortx8 hh[4];
#pragma unroll
        for (int s = 0; s < 4; ++s) hh[s] = H8[(size_t)idx[s] * 32 + q];
#pragma unroll
        for (int k = 0; k < 8; ++k) a0[k] += w[0] * bf2f(hh[0][k]);
#pragma unroll
        for (int k = 0; k < 8; ++k) a1[k] += w[1] * bf2f(hh[1][k]);
#pragma unroll
        for (int k = 0; k < 8; ++k) a0[k] += w[2] * bf2f(hh[2][k]);
#pragma unroll
        for (int k = 0; k < 8; ++k) a1[k] += w[3] * bf2f(hh[3][k]);
    }
#pragma unroll
    for (int k = 0; k < 8; ++k) a0[k] += a1[k];
#pragma unroll
    for (int k = 0; k < 8; ++k) a0[k] += __shfl_xor(a0[k], 32, 64);

    if (h == 0) {
        ushortx8 o = {f2bf(a0[0]), f2bf(a0[1]), f2bf(a0[2]), f2bf(a0[3]),
                      f2bf(a0[4]), f2bf(a0[5]), f2bf(a0[6]), f2bf(a0[7])};
        __builtin_nontemporal_store(o, (ushortx8*)OUT + (size_t)i * 32 + q);
    }
}

// ---------------- layer-1 MFMA GEMM: f1 = relu(ag0[N,128] @ [Wp1|Wv1] + b) -------
__global__ __launch_bounds__(256) void k_gemm1(const ushort_t* __restrict__ A,
                                               const ushort_t* __restrict__ Wt1,
                                               const float* __restrict__ bL,
                                               const float* __restrict__ bH,
                                               ushort_t* __restrict__ C, int nrows) {
    __shared__ ushort_t Wl[256 * 128];
    int t = threadIdx.x;
    const ushortx8* Wg = (const ushortx8*)Wt1;
#pragma unroll
    for (int i = 0; i < 16; ++i) {
        int c = i * 256 + t;
        int row = c >> 4, slot = c & 15;
        int db = row * 256 + ((slot * 16) ^ ((row & 7) << 4));
        *(ushortx8*)((char*)Wl + db) = Wg[c];
    }
    __syncthreads();

    int w = t >> 6, l = t & 63, m = l & 15, g = l >> 4;
    int r0 = blockIdx.x * 64 + w * 16;
    if (r0 >= nrows) return;

    const ushort_t* Arow = A + (size_t)(r0 + m) * 128;
    bf16x8 af[4];
#pragma unroll
    for (int kk = 0; kk < 4; ++kk) af[kk] = *(const bf16x8*)(Arow + kk * 32 + g * 8);

    f32x4 acc[16];
#pragma unroll
    for (int nt = 0; nt < 16; ++nt) acc[nt] = (f32x4){0.f, 0.f, 0.f, 0.f};
    int sw = (m & 7) << 4;
#pragma unroll
    for (int nt = 0; nt < 16; ++nt) {
        const char* Wb = (const char*)Wl + (nt * 16 + m) * 256;
#pragma unroll
        for (int kk = 0; kk < 4; ++kk) {
            bf16x8 wf = *(const bf16x8*)(Wb + ((kk * 64 + g * 16) ^ sw));
            acc[nt] = __builtin_amdgcn_mfma_f32_16x16x32_bf16(wf, af[kk], acc[nt], 0, 0, 0);
        }
    }
#pragma unroll
    for (int nt = 0; nt < 16; ++nt) {
        const float* bb = (nt < 8) ? (bL + nt * 16 + g * 4) : (bH + (nt - 8) * 16 + g * 4);
        float4 bv = *(const float4*)bb;
        ushortx4 o = {f2bf(fmaxf(acc[nt][0] + bv.x, 0.f)),
                      f2bf(fmaxf(acc[nt][1] + bv.y, 0.f)),
                      f2bf(fmaxf(acc[nt][2] + bv.z, 0.f)),
                      f2bf(fmaxf(acc[nt][3] + bv.w, 0.f))};
        *(ushortx4*)(C + (size_t)(r0 + m) * 256 + nt * 16 + g * 4) = o;
    }
}

// ---- layer-2 dual MFMA GEMM fused with layer-3 projection -----------------------
// f2 = relu(ag1 @ blockdiag(Wp2,Wv2) + b) computed in registers, then
// fs[:,0:8] = f2[:,0:128] @ Wp3 ; fs[:,8] = f2[:,128:256] @ Wv3. f2 never stored.
__global__ __launch_bounds__(256) void k_gemm2s(const ushort_t* __restrict__ A,
                                                const ushort_t* __restrict__ Wp,
                                                const ushort_t* __restrict__ Wv,
                                                const float* __restrict__ bL,
                                                const float* __restrict__ bH,
                                                const float* __restrict__ Wp3,
                                                const float* __restrict__ Wv3,
                                                float* __restrict__ FS, int nrows) {
    __shared__ ushort_t Wl[2 * 128 * 128];   // 64KB
    __shared__ float W3c[9][128];            // 4.5KB, SoA: W3c[c][k]
    int t = threadIdx.x;
    const ushortx8* Wgp = (const ushortx8*)Wp;
    const ushortx8* Wgv = (const ushortx8*)Wv;
#pragma unroll
    for (int i = 0; i < 8; ++i) {
        int c = i * 256 + t;
        int row = c >> 4, slot = c & 15;
        int db = row * 256 + ((slot * 16) ^ ((row & 7) << 4));
        *(ushortx8*)((char*)Wl + db) = Wgp[c];
        *(ushortx8*)((char*)Wl + 32768 + db) = Wgv[c];
    }
    for (int jj = t; jj < 1152; jj += 256) {
        int c = jj >> 7, k = jj & 127;
        W3c[c][k] = (c < 8) ? Wp3[k * 8 + c] : Wv3[k];
    }
    __syncthreads();

    int w = t >> 6, l = t & 63, m = l & 15, g = l >> 4;
    int r0 = blockIdx.x * 64 + w * 16;
    if (r0 >= nrows) return;

    const ushort_t* Arow = A + (size_t)(r0 + m) * 256;
    bf16x8 alo[4], ahi[4];
#pragma unroll
    for (int kk = 0; kk < 4; ++kk) {
        alo[kk] = *(const bf16x8*)(Arow + kk * 32 + g * 8);
        ahi[kk] = *(const bf16x8*)(Arow + 128 + kk * 32 + g * 8);
    }

    f32x4 accp[8], accv[8];
#pragma unroll
    for (int nt = 0; nt < 8; ++nt) {
        accp[nt] = (f32x4){0.f, 0.f, 0.f, 0.f};
        accv[nt] = (f32x4){0.f, 0.f, 0.f, 0.f};
    }
    int sw = (m & 7) << 4;
#pragma unroll
    for (int nt = 0; nt < 8; ++nt) {
        const char* Wbp = (const char*)Wl + (nt * 16 + m) * 256;
        const char* Wbv = Wbp + 32768;
#pragma unroll
        for (int kk = 0; kk < 4; ++kk) {
            int off = (kk * 64 + g * 16) ^ sw;
            bf16x8 wfp = *(const bf16x8*)(Wbp + off);
            accp[nt] = __builtin_amdgcn_mfma_f32_16x16x32_bf16(wfp, alo[kk], accp[nt], 0, 0, 0);
            bf16x8 wfv = *(const bf16x8*)(Wbv + off);
            accv[nt] = __builtin_amdgcn_mfma_f32_16x16x32_bf16(wfv, ahi[kk], accv[nt], 0, 0, 0);
        }
    }

    // bias + relu in registers (lane holds cols nt*16+g*4+j of row r0+m, both halves)
    float rp[8][4], rv[8][4];
#pragma unroll
    for (int nt = 0; nt < 8; ++nt) {
        float4 bp = *(const float4*)(bL + nt * 16 + g * 4);
        float4 bv = *(const float4*)(bH + nt * 16 + g * 4);
        rp[nt][0] = fmaxf(accp[nt][0] + bp.x, 0.f);
        rp[nt][1] = fmaxf(accp[nt][1] + bp.y, 0.f);
        rp[nt][2] = fmaxf(accp[nt][2] + bp.z, 0.f);
        rp[nt][3] = fmaxf(accp[nt][3] + bp.w, 0.f);
        rv[nt][0] = fmaxf(accv[nt][0] + bv.x, 0.f);
        rv[nt][1] = fmaxf(accv[nt][1] + bv.y, 0.f);
        rv[nt][2] = fmaxf(accv[nt][2] + bv.z, 0.f);
        rv[nt][3] = fmaxf(accv[nt][3] + bv.w, 0.f);
    }

    // project to 9 outputs: partial over this lane's 32 k's, then reduce over g
    float ps[9] = {};
#pragma unroll
    for (int c = 0; c < 8; ++c) {
#pragma unroll
        for (int nt = 0; nt < 8; ++nt) {
            float4 w4 = *(const float4*)&W3c[c][nt * 16 + g * 4];
            ps[c] += rp[nt][0] * w4.x + rp[nt][1] * w4.y + rp[nt][2] * w4.z + rp[nt][3] * w4.w;
        }
    }
#pragma unroll
    for (int nt = 0; nt < 8; ++nt) {
        float4 w4 = *(const float4*)&W3c[8][nt * 16 + g * 4];
        ps[8] += rv[nt][0] * w4.x + rv[nt][1] * w4.y + rv[nt][2] * w4.z + rv[nt][3] * w4.w;
    }
#pragma unroll
    for (int c = 0; c < 9; ++c) {
        ps[c] += __shfl_xor(ps[c], 16, 64);
        ps[c] += __shfl_xor(ps[c], 32, 64);
    }
    if (g == 0) {
        float* o = FS + (size_t)(r0 + m) * 12;
        fltx4 o0 = {ps[0], ps[1], ps[2], ps[3]};
        fltx4 o1 = {ps[4], ps[5], ps[6], ps[7]};
        __builtin_nontemporal_store(o0, (fltx4*)o);
        __builtin_nontemporal_store(o1, (fltx4*)o + 1);
        __builtin_nontemporal_store(ps[8], o + 8);
    }
}

// ---------------- final fused aggregation (8 logits + 1 value) ----------------
__global__ void k_agg9(const float* __restrict__ FS, float* __restrict__ out_logits,
                       float* __restrict__ out_v, const float* __restrict__ bp3,
                       const float* __restrict__ bv3, const float* __restrict__ dinv,
                       const int2* __restrict__ rc, const int2* __restrict__ edges) {
    int i = blockIdx.x * 256 + threadIdx.x;
    if (i >= NN) return;
    float di = dinv[i];
    float w0 = di * di;
    const float4* F = (const float4*)FS;
    size_t b0 = (size_t)i * 3;
    float4 x0 = F[b0], x1 = F[b0 + 1], x2 = F[b0 + 2];
    float a[9];
    a[0] = w0 * x0.x; a[1] = w0 * x0.y; a[2] = w0 * x0.z; a[3] = w0 * x0.w;
    a[4] = w0 * x1.x; a[5] = w0 * x1.y; a[6] = w0 * x1.z; a[7] = w0 * x1.w;
    a[8] = w0 * x2.x;
    int2 rcv = rc[i];
    int st = rcv.x, n = rcv.y;
    for (int j = 0; j < n; ++j) {
        int2 e = edges[st + j];
        float w = __int_as_float(e.y);
        size_t sb = (size_t)e.x * 3;
        float4 y0 = F[sb], y1 = F[sb + 1], y2 = F[sb + 2];
        a[0] += w * y0.x; a[1] += w * y0.y; a[2] += w * y0.z; a[3] += w * y0.w;
        a[4] += w * y1.x; a[5] += w * y1.y; a[6] += w * y1.z; a[7] += w * y1.w;
        a[8] += w * y2.x;
    }
    float4 bpa = *(const float4*)bp3;
    float4 bpb = *(const float4*)(bp3 + 4);
    fltx4 o0 = {a[0] + bpa.x, a[1] + bpa.y, a[2] + bpa.z, a[3] + bpa.w};
    fltx4 o1 = {a[4] + bpb.x, a[5] + bpb.y, a[6] + bpb.z, a[7] + bpb.w};
    __builtin_nontemporal_store(o0, (fltx4*)out_logits + (size_t)i * 2);
    __builtin_nontemporal_store(o1, (fltx4*)out_logits + (size_t)i * 2 + 1);
    __builtin_nontemporal_store(a[8] + bv3[0], out_v + i);
}

// ---------------- launcher ----------------
extern "C" void kernel_launch(void* const* d_in, const int* in_sizes, int n_in,
                              void* d_out, int out_size, void* d_ws, size_t ws_size,
                              hipStream_t stream) {
    const float* x   = (const float*)d_in[0];
    const int*   ei  = (const int*)d_in[1];
    const float* Wp1 = (const float*)d_in[2],  *bp1 = (const float*)d_in[3];
    const float* Wp2 = (const float*)d_in[4],  *bp2 = (const float*)d_in[5];
    const float* Wp3 = (const float*)d_in[6],  *bp3 = (const float*)d_in[7];
    const float* Wv1 = (const float*)d_in[8],  *bv1 = (const float*)d_in[9];
    const float* Wv2 = (const float*)d_in[10], *bv2 = (const float*)d_in[11];
    const float* Wv3 = (const float*)d_in[12], *bv3 = (const float*)d_in[13];
    float* out_logits = (float*)d_out;
    float* out_v = (float*)d_out + (size_t)NN * 8;

    char* w = (char*)d_ws;
    auto alloc = [&](size_t bytes) {
        char* p = w;
        w += (bytes + 255) & ~(size_t)255;
        return p;
    };
    int*      cntfill = (int*)alloc((size_t)2 * NN * 4);
    int*      cnt    = cntfill;
    int*      fill   = cntfill + NN;
    int*      rowptr = (int*)alloc(NN * 4);
    int*      bsum   = (int*)alloc(256 * 4);
    int*      boff   = (int*)alloc(256 * 4);
    float*    dinv   = (float*)alloc(NN * 4);
    int2*     rc     = (int2*)alloc((size_t)NN * 8);
    int2*     edges  = (int2*)alloc((size_t)NE * 8);
    ushort_t* Wt1    = (ushort_t*)alloc(256 * 128 * 2);
    ushort_t* Wt2p   = (ushort_t*)alloc(128 * 128 * 2);
    ushort_t* Wt2v   = (ushort_t*)alloc(128 * 128 * 2);
    ushort_t* xb     = (ushort_t*)alloc((size_t)NN * 128 * 2);
    ushort_t* ag0    = (ushort_t*)alloc((size_t)NN * 128 * 2);
    ushort_t* f1b    = (ushort_t*)alloc((size_t)NN * 256 * 2);
    ushort_t* ag1    = (ushort_t*)alloc((size_t)NN * 256 * 2);
    float*    fs     = (float*)alloc((size_t)NN * 12 * 4);

    const int NB = (NN + 255) / 256;   // 196
    const int EB = (NE + 255) / 256;   // 2344
    const int GB = (NN + 63) / 64;     // 782
    const int AB = NN / 4;             // 12500

    (void)hipMemsetAsync(cntfill, 0, (size_t)2 * NN * 4, stream);
    k_pre<<<3125 + EB, 256, 0, stream>>>(x, xb, ei, cnt);
    k_scan1<<<NB, 256, 0, stream>>>(cnt, rowptr, bsum, dinv);
    k_scan2_prep<<<257, 256, 0, stream>>>(bsum, boff, NB, Wp1, Wv1, Wp2, Wv2,
                                          Wt1, Wt2p, Wt2v);
    k_scan3rc<<<NB, 256, 0, stream>>>(rowptr, cnt, boff, rc);
    k_fill<<<EB, 256, 0, stream>>>(ei, rc, fill, dinv, edges);

    // layer 1: agg(x) then GEMM (+bias+relu)   [agg(x@W) == agg(x)@W]
    k_agg128<<<AB, 256, 0, stream>>>(xb, ag0, dinv, rc, edges);
    k_gemm1<<<GB, 256, 0, stream>>>(ag0, Wt1, bp1, bv1, f1b, NN);
    // layer 2: agg(f1), then fused {GEMM2 + bias + relu + layer-3 projection}
    k_agg256<<<AB, 256, 0, stream>>>(f1b, ag1, dinv, rc, edges);
    k_gemm2s<<<GB, 256, 0, stream>>>(ag1, Wt2p, Wt2v, bp2, bv2, Wp3, Wv3, fs, NN);
    // layer 3 gather
    k_agg9<<<NB, 256, 0, stream>>>(fs, out_logits, out_v, bp3, bv3, dinv, rc, edges);
}

// Round 11
// 203.388 us; speedup vs baseline: 1.1281x; 1.0177x over previous
//
#include <hip/hip_runtime.h>

#define NN 50000
#define NE 600000
#define EBLK 2344   // (NE+255)/256

typedef unsigned short ushort_t;
typedef ushort_t ushortx8 __attribute__((ext_vector_type(8)));
typedef ushort_t ushortx4 __attribute__((ext_vector_type(4)));
typedef short bf16x8 __attribute__((ext_vector_type(8)));
typedef float f32x4 __attribute__((ext_vector_type(4)));
typedef int intx2 __attribute__((ext_vector_type(2)));
typedef float fltx4 __attribute__((ext_vector_type(4)));

__device__ __forceinline__ float bf2f(ushort_t u) {
    union { unsigned int i; float f; } c;
    c.i = ((unsigned int)u) << 16;
    return c.f;
}
__device__ __forceinline__ ushort_t f2bf(float f) {
    union { float f; unsigned int i; } c;
    c.f = f;
    unsigned int u = c.i;
    unsigned int r = u + 0x7FFFu + ((u >> 16) & 1u);   // RNE
    return (ushort_t)(r >> 16);
}
__device__ __forceinline__ unsigned cvtpk(float lo, float hi) {
    unsigned r;
    asm("v_cvt_pk_bf16_f32 %0, %1, %2" : "=v"(r) : "v"(lo), "v"(hi));
    return r;
}

// -------- merged: x->bf16 | degree count | weight prep (all independent) --------
__global__ void k_pre(const float* __restrict__ X, ushort_t* __restrict__ XB,
                      const int* __restrict__ ei, int* __restrict__ cnt,
                      const float* __restrict__ Wp1, const float* __restrict__ Wv1,
                      const float* __restrict__ Wp2, const float* __restrict__ Wv2,
                      ushort_t* __restrict__ Wt1, ushort_t* __restrict__ Wt2p,
                      ushort_t* __restrict__ Wt2v) {
    int b = blockIdx.x, t = threadIdx.x;
    if (b < 3125) {
        size_t i = (size_t)b * 256 + t;
        const float4* X4 = (const float4*)X;
        float4 a = X4[i * 2], c4 = X4[i * 2 + 1];
        union { unsigned u[4]; ushortx8 v; } cv;
        cv.u[0] = cvtpk(a.x, a.y);
        cv.u[1] = cvtpk(a.z, a.w);
        cv.u[2] = cvtpk(c4.x, c4.y);
        cv.u[3] = cvtpk(c4.z, c4.w);
        ((ushortx8*)XB)[i] = cv.v;     // plain store: xb is gathered next, keep in L2
    } else if (b < 3125 + EBLK) {
        int e = (b - 3125) * 256 + t;
        if (e < NE) {
            int d = __builtin_nontemporal_load(ei + NE + e);
            atomicAdd(&cnt[d], 1);
        }
    } else {
        int wb = b - 3125 - EBLK;      // 0..255
        if (wb < 128) {
            int idx = wb * 256 + t;
            int n = idx >> 7, k = idx & 127;
            float v = (n < 128) ? Wp1[k * 128 + n] : Wv1[k * 128 + (n - 128)];
            Wt1[n * 128 + k] = f2bf(v);
        } else if (wb < 192) {
            int idx = (wb - 128) * 256 + t;
            int n = idx >> 7, k = idx & 127;
            Wt2p[n * 128 + k] = f2bf(Wp2[k * 128 + n]);
        } else {
            int idx = (wb - 192) * 256 + t;
            int n = idx >> 7, k = idx & 127;
            Wt2v[n * 128 + k] = f2bf(Wv2[k * 128 + n]);
        }
    }
}

// -------- single-pass scan: rc[i]={base+excl, cnt} via atomic block offset ------
// (CSR segment order becomes block-arrival order -- valid permutation, sums unchanged)
__global__ void k_scanrc(const int* __restrict__ cnt, float* __restrict__ dinv,
                         int2* __restrict__ rc, int* __restrict__ gofs) {
    __shared__ int s[256];
    __shared__ int base;
    int t = threadIdx.x;
    int i = blockIdx.x * 256 + t;
    int v = (i < NN) ? cnt[i] : 0;
    if (i < NN) dinv[i] = rsqrtf(1.0f + (float)v);
    s[t] = v;
    __syncthreads();
    for (int d = 1; d < 256; d <<= 1) {
        int tmp = (t >= d) ? s[t - d] : 0;
        __syncthreads();
        s[t] += tmp;
        __syncthreads();
    }
    if (t == 255) base = atomicAdd(gofs, s[255]);
    __syncthreads();
    if (i < NN) {
        int2 o;
        o.x = base + s[t] - v;
        o.y = v;
        rc[i] = o;
    }
}

// scatter {src, weight} into CSR slots
__global__ void k_fill(const int* __restrict__ ei, const int2* __restrict__ rc,
                       int* __restrict__ fill, const float* __restrict__ dinv,
                       int2* __restrict__ edges) {
    int e = blockIdx.x * 256 + threadIdx.x;
    if (e < NE) {
        int s = __builtin_nontemporal_load(ei + e);
        int d = __builtin_nontemporal_load(ei + NE + e);
        int pos = rc[d].x + atomicAdd(&fill[d], 1);
        int2 pr;
        pr.x = s;
        pr.y = __float_as_int(dinv[s] * dinv[d]);
        edges[pos] = pr;
    }
}

// ---------------- aggregation, 128 features bf16 (layer-1 input x) --------------
__global__ __launch_bounds__(256) void k_agg128(const ushort_t* __restrict__ H,
                                                ushort_t* __restrict__ OUT,
                                                const float* __restrict__ dinv,
                                                const int2* __restrict__ rc,
                                                const int2* __restrict__ edges) {
    int wv = threadIdx.x >> 6;
    int l = threadIdx.x & 63;
    int i = blockIdx.x * 4 + wv;
    if (i >= NN) return;
    int t2 = l >> 4, q = l & 15;
    const ushortx8* H8 = (const ushortx8*)H;

    float a0[8] = {}, a1[8] = {};
    float di = dinv[i];
    float ws = (t2 == 0) ? di * di : 0.f;
    ushortx8 hv = H8[(size_t)i * 16 + q];
#pragma unroll
    for (int k = 0; k < 8; ++k) a0[k] = ws * bf2f(hv[k]);

    int2 rcv = rc[i];
    int st = rcv.x, n = rcv.y;

    for (int j = t2; j < n; j += 16) {
        int idx[4];
        float w[4];
#pragma unroll
        for (int s = 0; s < 4; ++s) {
            int jj = j + 4 * s;
            bool valid = jj < n;
            intx2 em = __builtin_nontemporal_load(
                (const intx2*)edges + (valid ? st + jj : st));
            idx[s] = valid ? em.x : i;
            w[s] = valid ? __int_as_float(em.y) : 0.f;
        }
        ushortx8 hh[4];
#pragma unroll
        for (int s = 0; s < 4; ++s) hh[s] = H8[(size_t)idx[s] * 16 + q];
#pragma unroll
        for (int k = 0; k < 8; ++k) a0[k] += w[0] * bf2f(hh[0][k]);
#pragma unroll
        for (int k = 0; k < 8; ++k) a1[k] += w[1] * bf2f(hh[1][k]);
#pragma unroll
        for (int k = 0; k < 8; ++k) a0[k] += w[2] * bf2f(hh[2][k]);
#pragma unroll
        for (int k = 0; k < 8; ++k) a1[k] += w[3] * bf2f(hh[3][k]);
    }
#pragma unroll
    for (int k = 0; k < 8; ++k) a0[k] += a1[k];
#pragma unroll
    for (int k = 0; k < 8; ++k) {
        a0[k] += __shfl_xor(a0[k], 16, 64);
        a0[k] += __shfl_xor(a0[k], 32, 64);
    }
    if (l < 16) {
        ushortx8 o = {f2bf(a0[0]), f2bf(a0[1]), f2bf(a0[2]), f2bf(a0[3]),
                      f2bf(a0[4]), f2bf(a0[5]), f2bf(a0[6]), f2bf(a0[7])};
        ((ushortx8*)OUT)[(size_t)i * 16 + q] = o;   // plain: gemm1 reads next
    }
}

// ---------------- aggregation, 256 features bf16 ----------
__global__ __launch_bounds__(256) void k_agg256(const ushort_t* __restrict__ H,
                                                ushort_t* __restrict__ OUT,
                                                const float* __restrict__ dinv,
                                                const int2* __restrict__ rc,
                                                const int2* __restrict__ edges) {
    int wv = threadIdx.x >> 6;
    int l = threadIdx.x & 63;
    int i = blockIdx.x * 4 + wv;
    if (i >= NN) return;
    int h = l >> 5, q = l & 31;
    const ushortx8* H8 = (const ushortx8*)H;

    float a0[8] = {}, a1[8] = {};
    float di = dinv[i];
    float ws = (h == 0) ? di * di : 0.f;
    ushortx8 hv = H8[(size_t)i * 32 + q];
#pragma unroll
    for (int k = 0; k < 8; ++k) a0[k] = ws * bf2f(hv[k]);

    int2 rcv = rc[i];
    int st = rcv.x, n = rcv.y;

    for (int j = h; j < n; j += 8) {
        int idx[4];
        float w[4];
#pragma unroll
        for (int s = 0; s < 4; ++s) {
            int jj = j + 2 * s;
            bool valid = jj < n;
            intx2 em = __builtin_nontemporal_load(
                (const intx2*)edges + (valid ? st + jj : st));
            idx[s] = valid ? em.x : i;
            w[s] = valid ? __int_as_float(em.y) : 0.f;
        }
        ushortx8 hh[4];
#pragma unroll
        for (int s = 0; s < 4; ++s) hh[s] = H8[(size_t)idx[s] * 32 + q];
#pragma unroll
        for (int k = 0; k < 8; ++k) a0[k] += w[0] * bf2f(hh[0][k]);
#pragma unroll
        for (int k = 0; k < 8; ++k) a1[k] += w[1] * bf2f(hh[1][k]);
#pragma unroll
        for (int k = 0; k < 8; ++k) a0[k] += w[2] * bf2f(hh[2][k]);
#pragma unroll
        for (int k = 0; k < 8; ++k) a1[k] += w[3] * bf2f(hh[3][k]);
    }
#pragma unroll
    for (int k = 0; k < 8; ++k) a0[k] += a1[k];
#pragma unroll
    for (int k = 0; k < 8; ++k) a0[k] += __shfl_xor(a0[k], 32, 64);

    if (h == 0) {
        ushortx8 o = {f2bf(a0[0]), f2bf(a0[1]), f2bf(a0[2]), f2bf(a0[3]),
                      f2bf(a0[4]), f2bf(a0[5]), f2bf(a0[6]), f2bf(a0[7])};
        ((ushortx8*)OUT)[(size_t)i * 32 + q] = o;   // plain: gemm2s reads next
    }
}

// ---------------- layer-1 MFMA GEMM: f1 = relu(ag0[N,128] @ [Wp1|Wv1] + b) -------
__global__ __launch_bounds__(256) void k_gemm1(const ushort_t* __restrict__ A,
                                               const ushort_t* __restrict__ Wt1,
                                               const float* __restrict__ bL,
                                               const float* __restrict__ bH,
                                               ushort_t* __restrict__ C, int nrows) {
    __shared__ ushort_t Wl[256 * 128];
    int t = threadIdx.x;
    const ushortx8* Wg = (const ushortx8*)Wt1;
#pragma unroll
    for (int i = 0; i < 16; ++i) {
        int c = i * 256 + t;
        int row = c >> 4, slot = c & 15;
        int db = row * 256 + ((slot * 16) ^ ((row & 7) << 4));
        *(ushortx8*)((char*)Wl + db) = Wg[c];
    }
    __syncthreads();

    int w = t >> 6, l = t & 63, m = l & 15, g = l >> 4;
    int r0 = blockIdx.x * 64 + w * 16;
    if (r0 >= nrows) return;

    const ushort_t* Arow = A + (size_t)(r0 + m) * 128;
    bf16x8 af[4];
#pragma unroll
    for (int kk = 0; kk < 4; ++kk) af[kk] = *(const bf16x8*)(Arow + kk * 32 + g * 8);

    f32x4 acc[16];
#pragma unroll
    for (int nt = 0; nt < 16; ++nt) acc[nt] = (f32x4){0.f, 0.f, 0.f, 0.f};
    int sw = (m & 7) << 4;
#pragma unroll
    for (int nt = 0; nt < 16; ++nt) {
        const char* Wb = (const char*)Wl + (nt * 16 + m) * 256;
#pragma unroll
        for (int kk = 0; kk < 4; ++kk) {
            bf16x8 wf = *(const bf16x8*)(Wb + ((kk * 64 + g * 16) ^ sw));
            acc[nt] = __builtin_amdgcn_mfma_f32_16x16x32_bf16(wf, af[kk], acc[nt], 0, 0, 0);
        }
    }
#pragma unroll
    for (int nt = 0; nt < 16; ++nt) {
        const float* bb = (nt < 8) ? (bL + nt * 16 + g * 4) : (bH + (nt - 8) * 16 + g * 4);
        float4 bv = *(const float4*)bb;
        ushortx4 o = {f2bf(fmaxf(acc[nt][0] + bv.x, 0.f)),
                      f2bf(fmaxf(acc[nt][1] + bv.y, 0.f)),
                      f2bf(fmaxf(acc[nt][2] + bv.z, 0.f)),
                      f2bf(fmaxf(acc[nt][3] + bv.w, 0.f))};
        *(ushortx4*)(C + (size_t)(r0 + m) * 256 + nt * 16 + g * 4) = o;
    }
}

// ---- layer-2 dual MFMA GEMM fused with layer-3 projection -----------------------
__global__ __launch_bounds__(256) void k_gemm2s(const ushort_t* __restrict__ A,
                                                const ushort_t* __restrict__ Wp,
                                                const ushort_t* __restrict__ Wv,
                                                const float* __restrict__ bL,
                                                const float* __restrict__ bH,
                                                const float* __restrict__ Wp3,
                                                const float* __restrict__ Wv3,
                                                float* __restrict__ FS, int nrows) {
    __shared__ ushort_t Wl[2 * 128 * 128];   // 64KB
    __shared__ float W3c[9][128];            // 4.5KB
    int t = threadIdx.x;
    const ushortx8* Wgp = (const ushortx8*)Wp;
    const ushortx8* Wgv = (const ushortx8*)Wv;
#pragma unroll
    for (int i = 0; i < 8; ++i) {
        int c = i * 256 + t;
        int row = c >> 4, slot = c & 15;
        int db = row * 256 + ((slot * 16) ^ ((row & 7) << 4));
        *(ushortx8*)((char*)Wl + db) = Wgp[c];
        *(ushortx8*)((char*)Wl + 32768 + db) = Wgv[c];
    }
    for (int jj = t; jj < 1152; jj += 256) {
        int c = jj >> 7, k = jj & 127;
        W3c[c][k] = (c < 8) ? Wp3[k * 8 + c] : Wv3[k];
    }
    __syncthreads();

    int w = t >> 6, l = t & 63, m = l & 15, g = l >> 4;
    int r0 = blockIdx.x * 64 + w * 16;
    if (r0 >= nrows) return;

    const ushort_t* Arow = A + (size_t)(r0 + m) * 256;
    bf16x8 alo[4], ahi[4];
#pragma unroll
    for (int kk = 0; kk < 4; ++kk) {
        alo[kk] = *(const bf16x8*)(Arow + kk * 32 + g * 8);
        ahi[kk] = *(const bf16x8*)(Arow + 128 + kk * 32 + g * 8);
    }

    f32x4 accp[8], accv[8];
#pragma unroll
    for (int nt = 0; nt < 8; ++nt) {
        accp[nt] = (f32x4){0.f, 0.f, 0.f, 0.f};
        accv[nt] = (f32x4){0.f, 0.f, 0.f, 0.f};
    }
    int sw = (m & 7) << 4;
#pragma unroll
    for (int nt = 0; nt < 8; ++nt) {
        const char* Wbp = (const char*)Wl + (nt * 16 + m) * 256;
        const char* Wbv = Wbp + 32768;
#pragma unroll
        for (int kk = 0; kk < 4; ++kk) {
            int off = (kk * 64 + g * 16) ^ sw;
            bf16x8 wfp = *(const bf16x8*)(Wbp + off);
            accp[nt] = __builtin_amdgcn_mfma_f32_16x16x32_bf16(wfp, alo[kk], accp[nt], 0, 0, 0);
            bf16x8 wfv = *(const bf16x8*)(Wbv + off);
            accv[nt] = __builtin_amdgcn_mfma_f32_16x16x32_bf16(wfv, ahi[kk], accv[nt], 0, 0, 0);
        }
    }

    float rp[8][4], rv[8][4];
#pragma unroll
    for (int nt = 0; nt < 8; ++nt) {
        float4 bp = *(const float4*)(bL + nt * 16 + g * 4);
        float4 bv = *(const float4*)(bH + nt * 16 + g * 4);
        rp[nt][0] = fmaxf(accp[nt][0] + bp.x, 0.f);
        rp[nt][1] = fmaxf(accp[nt][1] + bp.y, 0.f);
        rp[nt][2] = fmaxf(accp[nt][2] + bp.z, 0.f);
        rp[nt][3] = fmaxf(accp[nt][3] + bp.w, 0.f);
        rv[nt][0] = fmaxf(accv[nt][0] + bv.x, 0.f);
        rv[nt][1] = fmaxf(accv[nt][1] + bv.y, 0.f);
        rv[nt][2] = fmaxf(accv[nt][2] + bv.z, 0.f);
        rv[nt][3] = fmaxf(accv[nt][3] + bv.w, 0.f);
    }

    float ps[9] = {};
#pragma unroll
    for (int c = 0; c < 8; ++c) {
#pragma unroll
        for (int nt = 0; nt < 8; ++nt) {
            float4 w4 = *(const float4*)&W3c[c][nt * 16 + g * 4];
            ps[c] += rp[nt][0] * w4.x + rp[nt][1] * w4.y + rp[nt][2] * w4.z + rp[nt][3] * w4.w;
        }
    }
#pragma unroll
    for (int nt = 0; nt < 8; ++nt) {
        float4 w4 = *(const float4*)&W3c[8][nt * 16 + g * 4];
        ps[8] += rv[nt][0] * w4.x + rv[nt][1] * w4.y + rv[nt][2] * w4.z + rv[nt][3] * w4.w;
    }
#pragma unroll
    for (int c = 0; c < 9; ++c) {
        ps[c] += __shfl_xor(ps[c], 16, 64);
        ps[c] += __shfl_xor(ps[c], 32, 64);
    }
    if (g == 0) {
        // fs row stride 16 floats (64B, cacheline-aligned); plain stores keep it in L2
        float* o = FS + (size_t)(r0 + m) * 16;
        *(fltx4*)o = (fltx4){ps[0], ps[1], ps[2], ps[3]};
        *(fltx4*)(o + 4) = (fltx4){ps[4], ps[5], ps[6], ps[7]};
        o[8] = ps[8];
    }
}

// ---------------- final fused aggregation (8 logits + 1 value) ----------------
__global__ void k_agg9(const float* __restrict__ FS, float* __restrict__ out_logits,
                       float* __restrict__ out_v, const float* __restrict__ bp3,
                       const float* __restrict__ bv3, const float* __restrict__ dinv,
                       const int2* __restrict__ rc, const int2* __restrict__ edges) {
    int i = blockIdx.x * 256 + threadIdx.x;
    if (i >= NN) return;
    float di = dinv[i];
    float w0 = di * di;
    const float4* F = (const float4*)FS;
    size_t b0 = (size_t)i * 4;         // stride 16 floats = 4 float4
    float4 x0 = F[b0], x1 = F[b0 + 1];
    float x2 = FS[(size_t)i * 16 + 8];
    float a[9];
    a[0] = w0 * x0.x; a[1] = w0 * x0.y; a[2] = w0 * x0.z; a[3] = w0 * x0.w;
    a[4] = w0 * x1.x; a[5] = w0 * x1.y; a[6] = w0 * x1.z; a[7] = w0 * x1.w;
    a[8] = w0 * x2;
    int2 rcv = rc[i];
    int st = rcv.x, n = rcv.y;
    for (int j = 0; j < n; ++j) {
        int2 e = edges[st + j];
        float w = __int_as_float(e.y);
        size_t sb = (size_t)e.x * 4;
        float4 y0 = F[sb], y1 = F[sb + 1];
        float y2 = FS[(size_t)e.x * 16 + 8];
        a[0] += w * y0.x; a[1] += w * y0.y; a[2] += w * y0.z; a[3] += w * y0.w;
        a[4] += w * y1.x; a[5] += w * y1.y; a[6] += w * y1.z; a[7] += w * y1.w;
        a[8] += w * y2;
    }
    float4 bpa = *(const float4*)bp3;
    float4 bpb = *(const float4*)(bp3 + 4);
    fltx4 o0 = {a[0] + bpa.x, a[1] + bpa.y, a[2] + bpa.z, a[3] + bpa.w};
    fltx4 o1 = {a[4] + bpb.x, a[5] + bpb.y, a[6] + bpb.z, a[7] + bpb.w};
    __builtin_nontemporal_store(o0, (fltx4*)out_logits + (size_t)i * 2);
    __builtin_nontemporal_store(o1, (fltx4*)out_logits + (size_t)i * 2 + 1);
    __builtin_nontemporal_store(a[8] + bv3[0], out_v + i);
}

// ---------------- launcher ----------------
extern "C" void kernel_launch(void* const* d_in, const int* in_sizes, int n_in,
                              void* d_out, int out_size, void* d_ws, size_t ws_size,
                              hipStream_t stream) {
    const float* x   = (const float*)d_in[0];
    const int*   ei  = (const int*)d_in[1];
    const float* Wp1 = (const float*)d_in[2],  *bp1 = (const float*)d_in[3];
    const float* Wp2 = (const float*)d_in[4],  *bp2 = (const float*)d_in[5];
    const float* Wp3 = (const float*)d_in[6],  *bp3 = (const float*)d_in[7];
    const float* Wv1 = (const float*)d_in[8],  *bv1 = (const float*)d_in[9];
    const float* Wv2 = (const float*)d_in[10], *bv2 = (const float*)d_in[11];
    const float* Wv3 = (const float*)d_in[12], *bv3 = (const float*)d_in[13];
    float* out_logits = (float*)d_out;
    float* out_v = (float*)d_out + (size_t)NN * 8;

    char* w = (char*)d_ws;
    auto alloc = [&](size_t bytes) {
        char* p = w;
        w += (bytes + 255) & ~(size_t)255;
        return p;
    };
    int*      zeroed = (int*)alloc(((size_t)2 * NN + 256) * 4);  // cnt | fill | gofs
    int*      cnt    = zeroed;
    int*      fill   = zeroed + NN;
    int*      gofs   = zeroed + 2 * NN;
    float*    dinv   = (float*)alloc(NN * 4);
    int2*     rc     = (int2*)alloc((size_t)NN * 8);
    int2*     edges  = (int2*)alloc((size_t)NE * 8);
    ushort_t* Wt1    = (ushort_t*)alloc(256 * 128 * 2);
    ushort_t* Wt2p   = (ushort_t*)alloc(128 * 128 * 2);
    ushort_t* Wt2v   = (ushort_t*)alloc(128 * 128 * 2);
    ushort_t* xb     = (ushort_t*)alloc((size_t)NN * 128 * 2);
    ushort_t* ag0    = (ushort_t*)alloc((size_t)NN * 128 * 2);
    ushort_t* f1b    = (ushort_t*)alloc((size_t)NN * 256 * 2);
    ushort_t* ag1    = (ushort_t*)alloc((size_t)NN * 256 * 2);
    float*    fs     = (float*)alloc((size_t)NN * 16 * 4);

    const int NB = (NN + 255) / 256;   // 196
    const int GB = (NN + 63) / 64;     // 782
    const int AB = NN / 4;             // 12500

    (void)hipMemsetAsync(zeroed, 0, ((size_t)2 * NN + 256) * 4, stream);
    k_pre<<<3125 + EBLK + 256, 256, 0, stream>>>(x, xb, ei, cnt, Wp1, Wv1, Wp2, Wv2,
                                                 Wt1, Wt2p, Wt2v);
    k_scanrc<<<NB, 256, 0, stream>>>(cnt, dinv, rc, gofs);
    k_fill<<<EBLK, 256, 0, stream>>>(ei, rc, fill, dinv, edges);

    // layer 1: agg(x) then GEMM (+bias+relu)   [agg(x@W) == agg(x)@W]
    k_agg128<<<AB, 256, 0, stream>>>(xb, ag0, dinv, rc, edges);
    k_gemm1<<<GB, 256, 0, stream>>>(ag0, Wt1, bp1, bv1, f1b, NN);
    // layer 2: agg(f1), then fused {GEMM2 + bias + relu + layer-3 projection}
    k_agg256<<<AB, 256, 0, stream>>>(f1b, ag1, dinv, rc, edges);
    k_gemm2s<<<GB, 256, 0, stream>>>(ag1, Wt2p, Wt2v, bp2, bv2, Wp3, Wv3, fs, NN);
    // layer 3 gather
    k_agg9<<<NB, 256, 0, stream>>>(fs, out_logits, out_v, bp3, bv3, dinv, rc, edges);
}

// Round 13
// 202.367 us; speedup vs baseline: 1.1338x; 1.0050x over previous
//
#include <hip/hip_runtime.h>

#define NN 50000
#define NE 600000
#define EBLK 2344   // (NE+255)/256

typedef unsigned short ushort_t;
typedef ushort_t ushortx8 __attribute__((ext_vector_type(8)));
typedef ushort_t ushortx4 __attribute__((ext_vector_type(4)));
typedef short bf16x8 __attribute__((ext_vector_type(8)));
typedef float f32x4 __attribute__((ext_vector_type(4)));
typedef int intx2 __attribute__((ext_vector_type(2)));
typedef float fltx4 __attribute__((ext_vector_type(4)));

__device__ __forceinline__ float bf2f(ushort_t u) {
    union { unsigned int i; float f; } c;
    c.i = ((unsigned int)u) << 16;
    return c.f;
}
__device__ __forceinline__ ushort_t f2bf(float f) {
    union { float f; unsigned int i; } c;
    c.f = f;
    unsigned int u = c.i;
    unsigned int r = u + 0x7FFFu + ((u >> 16) & 1u);   // RNE
    return (ushort_t)(r >> 16);
}
__device__ __forceinline__ unsigned cvtpk(float lo, float hi) {
    unsigned r;
    asm("v_cvt_pk_bf16_f32 %0, %1, %2" : "=v"(r) : "v"(lo), "v"(hi));
    return r;
}

// -------- merged: x->bf16 | degree count | weight prep (all independent) --------
__global__ void k_pre(const float* __restrict__ X, ushort_t* __restrict__ XB,
                      const int* __restrict__ ei, int* __restrict__ cnt,
                      const float* __restrict__ Wp1, const float* __restrict__ Wv1,
                      const float* __restrict__ Wp2, const float* __restrict__ Wv2,
                      ushort_t* __restrict__ Wt1, ushort_t* __restrict__ Wt2p,
                      ushort_t* __restrict__ Wt2v) {
    int b = blockIdx.x, t = threadIdx.x;
    if (b < 3125) {
        size_t i = (size_t)b * 256 + t;
        const float4* X4 = (const float4*)X;
        float4 a = X4[i * 2], c4 = X4[i * 2 + 1];
        union { unsigned u[4]; ushortx8 v; } cv;
        cv.u[0] = cvtpk(a.x, a.y);
        cv.u[1] = cvtpk(a.z, a.w);
        cv.u[2] = cvtpk(c4.x, c4.y);
        cv.u[3] = cvtpk(c4.z, c4.w);
        ((ushortx8*)XB)[i] = cv.v;     // plain store: xb is gathered next, keep in L2
    } else if (b < 3125 + EBLK) {
        int e = (b - 3125) * 256 + t;
        if (e < NE) {
            int d = __builtin_nontemporal_load(ei + NE + e);
            atomicAdd(&cnt[d], 1);
        }
    } else {
        int wb = b - 3125 - EBLK;      // 0..255
        if (wb < 128) {
            int idx = wb * 256 + t;
            int n = idx >> 7, k = idx & 127;
            float v = (n < 128) ? Wp1[k * 128 + n] : Wv1[k * 128 + (n - 128)];
            Wt1[n * 128 + k] = f2bf(v);
        } else if (wb < 192) {
            int idx = (wb - 128) * 256 + t;
            int n = idx >> 7, k = idx & 127;
            Wt2p[n * 128 + k] = f2bf(Wp2[k * 128 + n]);
        } else {
            int idx = (wb - 192) * 256 + t;
            int n = idx >> 7, k = idx & 127;
            Wt2v[n * 128 + k] = f2bf(Wv2[k * 128 + n]);
        }
    }
}

// -------- single-pass scan: rc[i]={base+excl, cnt} via atomic block offset ------
// (CSR segment order becomes block-arrival order -- valid permutation, sums unchanged)
__global__ void k_scanrc(const int* __restrict__ cnt, float* __restrict__ dinv,
                         int2* __restrict__ rc, int* __restrict__ gofs) {
    __shared__ int s[256];
    __shared__ int base;
    int t = threadIdx.x;
    int i = blockIdx.x * 256 + t;
    int v = (i < NN) ? cnt[i] : 0;
    if (i < NN) dinv[i] = rsqrtf(1.0f + (float)v);
    s[t] = v;
    __syncthreads();
    for (int d = 1; d < 256; d <<= 1) {
        int tmp = (t >= d) ? s[t - d] : 0;
        __syncthreads();
        s[t] += tmp;
        __syncthreads();
    }
    if (t == 255) base = atomicAdd(gofs, s[255]);
    __syncthreads();
    if (i < NN) {
        int2 o;
        o.x = base + s[t] - v;
        o.y = v;
        rc[i] = o;
    }
}

// scatter {src, weight} into CSR slots
__global__ void k_fill(const int* __restrict__ ei, const int2* __restrict__ rc,
                       int* __restrict__ fill, const float* __restrict__ dinv,
                       int2* __restrict__ edges) {
    int e = blockIdx.x * 256 + threadIdx.x;
    if (e < NE) {
        int s = __builtin_nontemporal_load(ei + e);
        int d = __builtin_nontemporal_load(ei + NE + e);
        int pos = rc[d].x + atomicAdd(&fill[d], 1);
        int2 pr;
        pr.x = s;
        pr.y = __float_as_int(dinv[s] * dinv[d]);
        edges[pos] = pr;
    }
}

// ---------------- aggregation, 128 features bf16 (layer-1 input x) --------------
__global__ __launch_bounds__(256) void k_agg128(const ushort_t* __restrict__ H,
                                                ushort_t* __restrict__ OUT,
                                                const float* __restrict__ dinv,
                                                const int2* __restrict__ rc,
                                                const int2* __restrict__ edges) {
    int wv = threadIdx.x >> 6;
    int l = threadIdx.x & 63;
    int i = blockIdx.x * 4 + wv;
    if (i >= NN) return;
    int t2 = l >> 4, q = l & 15;
    const ushortx8* H8 = (const ushortx8*)H;

    float a0[8] = {}, a1[8] = {};
    float di = dinv[i];
    float ws = (t2 == 0) ? di * di : 0.f;
    ushortx8 hv = H8[(size_t)i * 16 + q];
#pragma unroll
    for (int k = 0; k < 8; ++k) a0[k] = ws * bf2f(hv[k]);

    int2 rcv = rc[i];
    int st = rcv.x, n = rcv.y;

    for (int j = t2; j < n; j += 16) {
        int idx[4];
        float w[4];
#pragma unroll
        for (int s = 0; s < 4; ++s) {
            int jj = j + 4 * s;
            bool valid = jj < n;
            intx2 em = __builtin_nontemporal_load(
                (const intx2*)edges + (valid ? st + jj : st));
            idx[s] = valid ? em.x : i;
            w[s] = valid ? __int_as_float(em.y) : 0.f;
        }
        ushortx8 hh[4];
#pragma unroll
        for (int s = 0; s < 4; ++s) hh[s] = H8[(size_t)idx[s] * 16 + q];
#pragma unroll
        for (int k = 0; k < 8; ++k) a0[k] += w[0] * bf2f(hh[0][k]);
#pragma unroll
        for (int k = 0; k < 8; ++k) a1[k] += w[1] * bf2f(hh[1][k]);
#pragma unroll
        for (int k = 0; k < 8; ++k) a0[k] += w[2] * bf2f(hh[2][k]);
#pragma unroll
        for (int k = 0; k < 8; ++k) a1[k] += w[3] * bf2f(hh[3][k]);
    }
#pragma unroll
    for (int k = 0; k < 8; ++k) a0[k] += a1[k];
#pragma unroll
    for (int k = 0; k < 8; ++k) {
        a0[k] += __shfl_xor(a0[k], 16, 64);
        a0[k] += __shfl_xor(a0[k], 32, 64);
    }
    if (l < 16) {
        ushortx8 o = {f2bf(a0[0]), f2bf(a0[1]), f2bf(a0[2]), f2bf(a0[3]),
                      f2bf(a0[4]), f2bf(a0[5]), f2bf(a0[6]), f2bf(a0[7])};
        ((ushortx8*)OUT)[(size_t)i * 16 + q] = o;   // plain: gemm1 reads next
    }
}

// ---------------- aggregation, 256 features bf16 ----------
__global__ __launch_bounds__(256) void k_agg256(const ushort_t* __restrict__ H,
                                                ushort_t* __restrict__ OUT,
                                                const float* __restrict__ dinv,
                                                const int2* __restrict__ rc,
                                                const int2* __restrict__ edges) {
    int wv = threadIdx.x >> 6;
    int l = threadIdx.x & 63;
    int i = blockIdx.x * 4 + wv;
    if (i >= NN) return;
    int h = l >> 5, q = l & 31;
    const ushortx8* H8 = (const ushortx8*)H;

    float a0[8] = {}, a1[8] = {};
    float di = dinv[i];
    float ws = (h == 0) ? di * di : 0.f;
    ushortx8 hv = H8[(size_t)i * 32 + q];
#pragma unroll
    for (int k = 0; k < 8; ++k) a0[k] = ws * bf2f(hv[k]);

    int2 rcv = rc[i];
    int st = rcv.x, n = rcv.y;

    for (int j = h; j < n; j += 8) {
        int idx[4];
        float w[4];
#pragma unroll
        for (int s = 0; s < 4; ++s) {
            int jj = j + 2 * s;
            bool valid = jj < n;
            intx2 em = __builtin_nontemporal_load(
                (const intx2*)edges + (valid ? st + jj : st));
            idx[s] = valid ? em.x : i;
            w[s] = valid ? __int_as_float(em.y) : 0.f;
        }
        ushortx8 hh[4];
#pragma unroll
        for (int s = 0; s < 4; ++s) hh[s] = H8[(size_t)idx[s] * 32 + q];
#pragma unroll
        for (int k = 0; k < 8; ++k) a0[k] += w[0] * bf2f(hh[0][k]);
#pragma unroll
        for (int k = 0; k < 8; ++k) a1[k] += w[1] * bf2f(hh[1][k]);
#pragma unroll
        for (int k = 0; k < 8; ++k) a0[k] += w[2] * bf2f(hh[2][k]);
#pragma unroll
        for (int k = 0; k < 8; ++k) a1[k] += w[3] * bf2f(hh[3][k]);
    }
#pragma unroll
    for (int k = 0; k < 8; ++k) a0[k] += a1[k];
#pragma unroll
    for (int k = 0; k < 8; ++k) a0[k] += __shfl_xor(a0[k], 32, 64);

    if (h == 0) {
        ushortx8 o = {f2bf(a0[0]), f2bf(a0[1]), f2bf(a0[2]), f2bf(a0[3]),
                      f2bf(a0[4]), f2bf(a0[5]), f2bf(a0[6]), f2bf(a0[7])};
        ((ushortx8*)OUT)[(size_t)i * 32 + q] = o;   // plain: gemm2s reads next
    }
}

// ---------------- layer-1 MFMA GEMM: f1 = relu(ag0[N,128] @ [Wp1|Wv1] + b) -------
__global__ __launch_bounds__(256) void k_gemm1(const ushort_t* __restrict__ A,
                                               const ushort_t* __restrict__ Wt1,
                                               const float* __restrict__ bL,
                                               const float* __restrict__ bH,
                                               ushort_t* __restrict__ C, int nrows) {
    __shared__ ushort_t Wl[256 * 128];
    int t = threadIdx.x;
    const ushortx8* Wg = (const ushortx8*)Wt1;
#pragma unroll
    for (int i = 0; i < 16; ++i) {
        int c = i * 256 + t;
        int row = c >> 4, slot = c & 15;
        int db = row * 256 + ((slot * 16) ^ ((row & 7) << 4));
        *(ushortx8*)((char*)Wl + db) = Wg[c];
    }
    __syncthreads();

    int w = t >> 6, l = t & 63, m = l & 15, g = l >> 4;
    int r0 = blockIdx.x * 64 + w * 16;
    if (r0 >= nrows) return;

    const ushort_t* Arow = A + (size_t)(r0 + m) * 128;
    bf16x8 af[4];
#pragma unroll
    for (int kk = 0; kk < 4; ++kk) af[kk] = *(const bf16x8*)(Arow + kk * 32 + g * 8);

    f32x4 acc[16];
#pragma unroll
    for (int nt = 0; nt < 16; ++nt) acc[nt] = (f32x4){0.f, 0.f, 0.f, 0.f};
    int sw = (m & 7) << 4;
#pragma unroll
    for (int nt = 0; nt < 16; ++nt) {
        const char* Wb = (const char*)Wl + (nt * 16 + m) * 256;
#pragma unroll
        for (int kk = 0; kk < 4; ++kk) {
            bf16x8 wf = *(const bf16x8*)(Wb + ((kk * 64 + g * 16) ^ sw));
            acc[nt] = __builtin_amdgcn_mfma_f32_16x16x32_bf16(wf, af[kk], acc[nt], 0, 0, 0);
        }
    }
#pragma unroll
    for (int nt = 0; nt < 16; ++nt) {
        const float* bb = (nt < 8) ? (bL + nt * 16 + g * 4) : (bH + (nt - 8) * 16 + g * 4);
        float4 bv = *(const float4*)bb;
        ushortx4 o = {f2bf(fmaxf(acc[nt][0] + bv.x, 0.f)),
                      f2bf(fmaxf(acc[nt][1] + bv.y, 0.f)),
                      f2bf(fmaxf(acc[nt][2] + bv.z, 0.f)),
                      f2bf(fmaxf(acc[nt][3] + bv.w, 0.f))};
        *(ushortx4*)(C + (size_t)(r0 + m) * 256 + nt * 16 + g * 4) = o;
    }
}

// ---- layer-2 dual MFMA GEMM fused with layer-3 projection -----------------------
__global__ __launch_bounds__(256) void k_gemm2s(const ushort_t* __restrict__ A,
                                                const ushort_t* __restrict__ Wp,
                                                const ushort_t* __restrict__ Wv,
                                                const float* __restrict__ bL,
                                                const float* __restrict__ bH,
                                                const float* __restrict__ Wp3,
                                                const float* __restrict__ Wv3,
                                                float* __restrict__ FS, int nrows) {
    __shared__ ushort_t Wl[2 * 128 * 128];   // 64KB
    __shared__ float W3c[9][128];            // 4.5KB
    int t = threadIdx.x;
    const ushortx8* Wgp = (const ushortx8*)Wp;
    const ushortx8* Wgv = (const ushortx8*)Wv;
#pragma unroll
    for (int i = 0; i < 8; ++i) {
        int c = i * 256 + t;
        int row = c >> 4, slot = c & 15;
        int db = row * 256 + ((slot * 16) ^ ((row & 7) << 4));
        *(ushortx8*)((char*)Wl + db) = Wgp[c];
        *(ushortx8*)((char*)Wl + 32768 + db) = Wgv[c];
    }
    for (int jj = t; jj < 1152; jj += 256) {
        int c = jj >> 7, k = jj & 127;
        W3c[c][k] = (c < 8) ? Wp3[k * 8 + c] : Wv3[k];
    }
    __syncthreads();

    int w = t >> 6, l = t & 63, m = l & 15, g = l >> 4;
    int r0 = blockIdx.x * 64 + w * 16;
    if (r0 >= nrows) return;

    const ushort_t* Arow = A + (size_t)(r0 + m) * 256;
    bf16x8 alo[4], ahi[4];
#pragma unroll
    for (int kk = 0; kk < 4; ++kk) {
        alo[kk] = *(const bf16x8*)(Arow + kk * 32 + g * 8);
        ahi[kk] = *(const bf16x8*)(Arow + 128 + kk * 32 + g * 8);
    }

    f32x4 accp[8], accv[8];
#pragma unroll
    for (int nt = 0; nt < 8; ++nt) {
        accp[nt] = (f32x4){0.f, 0.f, 0.f, 0.f};
        accv[nt] = (f32x4){0.f, 0.f, 0.f, 0.f};
    }
    int sw = (m & 7) << 4;
#pragma unroll
    for (int nt = 0; nt < 8; ++nt) {
        const char* Wbp = (const char*)Wl + (nt * 16 + m) * 256;
        const char* Wbv = Wbp + 32768;
#pragma unroll
        for (int kk = 0; kk < 4; ++kk) {
            int off = (kk * 64 + g * 16) ^ sw;
            bf16x8 wfp = *(const bf16x8*)(Wbp + off);
            accp[nt] = __builtin_amdgcn_mfma_f32_16x16x32_bf16(wfp, alo[kk], accp[nt], 0, 0, 0);
            bf16x8 wfv = *(const bf16x8*)(Wbv + off);
            accv[nt] = __builtin_amdgcn_mfma_f32_16x16x32_bf16(wfv, ahi[kk], accv[nt], 0, 0, 0);
        }
    }

    float rp[8][4], rv[8][4];
#pragma unroll
    for (int nt = 0; nt < 8; ++nt) {
        float4 bp = *(const float4*)(bL + nt * 16 + g * 4);
        float4 bv = *(const float4*)(bH + nt * 16 + g * 4);
        rp[nt][0] = fmaxf(accp[nt][0] + bp.x, 0.f);
        rp[nt][1] = fmaxf(accp[nt][1] + bp.y, 0.f);
        rp[nt][2] = fmaxf(accp[nt][2] + bp.z, 0.f);
        rp[nt][3] = fmaxf(accp[nt][3] + bp.w, 0.f);
        rv[nt][0] = fmaxf(accv[nt][0] + bv.x, 0.f);
        rv[nt][1] = fmaxf(accv[nt][1] + bv.y, 0.f);
        rv[nt][2] = fmaxf(accv[nt][2] + bv.z, 0.f);
        rv[nt][3] = fmaxf(accv[nt][3] + bv.w, 0.f);
    }

    float ps[9] = {};
#pragma unroll
    for (int c = 0; c < 8; ++c) {
#pragma unroll
        for (int nt = 0; nt < 8; ++nt) {
            float4 w4 = *(const float4*)&W3c[c][nt * 16 + g * 4];
            ps[c] += rp[nt][0] * w4.x + rp[nt][1] * w4.y + rp[nt][2] * w4.z + rp[nt][3] * w4.w;
        }
    }
#pragma unroll
    for (int nt = 0; nt < 8; ++nt) {
        float4 w4 = *(const float4*)&W3c[8][nt * 16 + g * 4];
        ps[8] += rv[nt][0] * w4.x + rv[nt][1] * w4.y + rv[nt][2] * w4.z + rv[nt][3] * w4.w;
    }
#pragma unroll
    for (int c = 0; c < 9; ++c) {
        ps[c] += __shfl_xor(ps[c], 16, 64);
        ps[c] += __shfl_xor(ps[c], 32, 64);
    }
    if (g == 0) {
        // fs row stride 16 floats (64B, cacheline-aligned); plain stores keep it in L2
        float* o = FS + (size_t)(r0 + m) * 16;
        *(fltx4*)o = (fltx4){ps[0], ps[1], ps[2], ps[3]};
        *(fltx4*)(o + 4) = (fltx4){ps[4], ps[5], ps[6], ps[7]};
        o[8] = ps[8];
    }
}

// ---------------- final fused aggregation (8 logits + 1 value) ----------------
__global__ void k_agg9(const float* __restrict__ FS, float* __restrict__ out_logits,
                       float* __restrict__ out_v, const float* __restrict__ bp3,
                       const float* __restrict__ bv3, const float* __restrict__ dinv,
                       const int2* __restrict__ rc, const int2* __restrict__ edges) {
    int i = blockIdx.x * 256 + threadIdx.x;
    if (i >= NN) return;
    float di = dinv[i];
    float w0 = di * di;
    const float4* F = (const float4*)FS;
    size_t b0 = (size_t)i * 4;         // stride 16 floats = 4 float4
    float4 x0 = F[b0], x1 = F[b0 + 1];
    float x2 = FS[(size_t)i * 16 + 8];
    float a[9];
    a[0] = w0 * x0.x; a[1] = w0 * x0.y; a[2] = w0 * x0.z; a[3] = w0 * x0.w;
    a[4] = w0 * x1.x; a[5] = w0 * x1.y; a[6] = w0 * x1.z; a[7] = w0 * x1.w;
    a[8] = w0 * x2;
    int2 rcv = rc[i];
    int st = rcv.x, n = rcv.y;
    for (int j = 0; j < n; ++j) {
        int2 e = edges[st + j];
        float w = __int_as_float(e.y);
        size_t sb = (size_t)e.x * 4;
        float4 y0 = F[sb], y1 = F[sb + 1];
        float y2 = FS[(size_t)e.x * 16 + 8];
        a[0] += w * y0.x; a[1] += w * y0.y; a[2] += w * y0.z; a[3] += w * y0.w;
        a[4] += w * y1.x; a[5] += w * y1.y; a[6] += w * y1.z; a[7] += w * y1.w;
        a[8] += w * y2;
    }
    float4 bpa = *(const float4*)bp3;
    float4 bpb = *(const float4*)(bp3 + 4);
    fltx4 o0 = {a[0] + bpa.x, a[1] + bpa.y, a[2] + bpa.z, a[3] + bpa.w};
    fltx4 o1 = {a[4] + bpb.x, a[5] + bpb.y, a[6] + bpb.z, a[7] + bpb.w};
    __builtin_nontemporal_store(o0, (fltx4*)out_logits + (size_t)i * 2);
    __builtin_nontemporal_store(o1, (fltx4*)out_logits + (size_t)i * 2 + 1);
    __builtin_nontemporal_store(a[8] + bv3[0], out_v + i);
}

// ---------------- launcher ----------------
extern "C" void kernel_launch(void* const* d_in, const int* in_sizes, int n_in,
                              void* d_out, int out_size, void* d_ws, size_t ws_size,
                              hipStream_t stream) {
    const float* x   = (const float*)d_in[0];
    const int*   ei  = (const int*)d_in[1];
    const float* Wp1 = (const float*)d_in[2],  *bp1 = (const float*)d_in[3];
    const float* Wp2 = (const float*)d_in[4],  *bp2 = (const float*)d_in[5];
    const float* Wp3 = (const float*)d_in[6],  *bp3 = (const float*)d_in[7];
    const float* Wv1 = (const float*)d_in[8],  *bv1 = (const float*)d_in[9];
    const float* Wv2 = (const float*)d_in[10], *bv2 = (const float*)d_in[11];
    const float* Wv3 = (const float*)d_in[12], *bv3 = (const float*)d_in[13];
    float* out_logits = (float*)d_out;
    float* out_v = (float*)d_out + (size_t)NN * 8;

    char* w = (char*)d_ws;
    auto alloc = [&](size_t bytes) {
        char* p = w;
        w += (bytes + 255) & ~(size_t)255;
        return p;
    };
    int*      zeroed = (int*)alloc(((size_t)2 * NN + 256) * 4);  // cnt | fill | gofs
    int*      cnt    = zeroed;
    int*      fill   = zeroed + NN;
    int*      gofs   = zeroed + 2 * NN;
    float*    dinv   = (float*)alloc(NN * 4);
    int2*     rc     = (int2*)alloc((size_t)NN * 8);
    int2*     edges  = (int2*)alloc((size_t)NE * 8);
    ushort_t* Wt1    = (ushort_t*)alloc(256 * 128 * 2);
    ushort_t* Wt2p   = (ushort_t*)alloc(128 * 128 * 2);
    ushort_t* Wt2v   = (ushort_t*)alloc(128 * 128 * 2);
    ushort_t* xb     = (ushort_t*)alloc((size_t)NN * 128 * 2);
    ushort_t* ag0    = (ushort_t*)alloc((size_t)NN * 128 * 2);
    ushort_t* f1b    = (ushort_t*)alloc((size_t)NN * 256 * 2);
    ushort_t* ag1    = (ushort_t*)alloc((size_t)NN * 256 * 2);
    float*    fs     = (float*)alloc((size_t)NN * 16 * 4);

    const int NB = (NN + 255) / 256;   // 196
    const int GB = (NN + 63) / 64;     // 782
    const int AB = NN / 4;             // 12500

    (void)hipMemsetAsync(zeroed, 0, ((size_t)2 * NN + 256) * 4, stream);
    k_pre<<<3125 + EBLK + 256, 256, 0, stream>>>(x, xb, ei, cnt, Wp1, Wv1, Wp2, Wv2,
                                                 Wt1, Wt2p, Wt2v);
    k_scanrc<<<NB, 256, 0, stream>>>(cnt, dinv, rc, gofs);
    k_fill<<<EBLK, 256, 0, stream>>>(ei, rc, fill, dinv, edges);

    // layer 1: agg(x) then GEMM (+bias+relu)   [agg(x@W) == agg(x)@W]
    k_agg128<<<AB, 256, 0, stream>>>(xb, ag0, dinv, rc, edges);
    k_gemm1<<<GB, 256, 0, stream>>>(ag0, Wt1, bp1, bv1, f1b, NN);
    // layer 2: agg(f1), then fused {GEMM2 + bias + relu + layer-3 projection}
    k_agg256<<<AB, 256, 0, stream>>>(f1b, ag1, dinv, rc, edges);
    k_gemm2s<<<GB, 256, 0, stream>>>(ag1, Wt2p, Wt2v, bp2, bv2, Wp3, Wv3, fs, NN);
    // layer 3 gather
    k_agg9<<<NB, 256, 0, stream>>>(fs, out_logits, out_v, bp3, bv3, dinv, rc, edges);
}